// Round 1
// baseline (91.259 us; speedup 1.0000x reference)
//
#include <hip/hip_runtime.h>
#include <math.h>

#define NTOK 2048
#define CC   128
#define CPP  16
#define HH   8
#define DHH  16
#define NQW  32
#define NKW  128
#define PADW 48
#define NBW  64

__device__ __forceinline__ float sigm(float x) { return 1.0f / (1.0f + expf(-x)); }

// ---------------------------------------------------------------------------
// K1: per-row LN(x1), LN(x2)*gamma_s, a = sigmoid(sln@Wg_ada+bg_ada)*aln + sln@W_skip
//     then q=(a@Wq)*0.25, k=a@Wk, v=a@Wv, g=sigmoid(a@Wg+bg)
// block: 8 rows x 256 threads (32 threads/row, 4 cols/thread)
// ---------------------------------------------------------------------------
__global__ __launch_bounds__(256) void prep_kernel(
    const float* __restrict__ x1, const float* __restrict__ x2,
    const float* __restrict__ gamma_s,
    const float* __restrict__ Wg_ada, const float* __restrict__ bg_ada,
    const float* __restrict__ W_skip,
    const float* __restrict__ Wq, const float* __restrict__ Wk,
    const float* __restrict__ Wv, const float* __restrict__ Wg,
    const float* __restrict__ bg,
    float* __restrict__ qb, float* __restrict__ kb,
    float* __restrict__ vb, float* __restrict__ gb)
{
  __shared__ float sln[8][132];
  __shared__ float as_[8][132];
  const int tid = threadIdx.x;
  const int r   = tid >> 5;
  const int t   = tid & 31;
  const int row = blockIdx.x * 8 + r;
  const int c0  = t * 4;

  float4 v1 = *(const float4*)(x1 + (size_t)row * CC + c0);
  float4 v2 = *(const float4*)(x2 + (size_t)row * CC + c0);

  float s1 = v1.x + v1.y + v1.z + v1.w;
  float p1 = v1.x * v1.x + v1.y * v1.y + v1.z * v1.z + v1.w * v1.w;
  float s2 = v2.x + v2.y + v2.z + v2.w;
  float p2 = v2.x * v2.x + v2.y * v2.y + v2.z * v2.z + v2.w * v2.w;
#pragma unroll
  for (int m = 1; m < 32; m <<= 1) {
    s1 += __shfl_xor(s1, m);
    p1 += __shfl_xor(p1, m);
    s2 += __shfl_xor(s2, m);
    p2 += __shfl_xor(p2, m);
  }
  const float rc = 1.0f / (float)CC;
  float mu1 = s1 * rc, mu2 = s2 * rc;
  float rs1 = rsqrtf(p1 * rc - mu1 * mu1 + 1e-5f);
  float rs2 = rsqrtf(p2 * rc - mu2 * mu2 + 1e-5f);

  float4 gs = *(const float4*)(gamma_s + c0);
  float aln0 = (v1.x - mu1) * rs1;
  float aln1 = (v1.y - mu1) * rs1;
  float aln2 = (v1.z - mu1) * rs1;
  float aln3 = (v1.w - mu1) * rs1;
  sln[r][c0 + 0] = (v2.x - mu2) * rs2 * gs.x;
  sln[r][c0 + 1] = (v2.y - mu2) * rs2 * gs.y;
  sln[r][c0 + 2] = (v2.z - mu2) * rs2 * gs.z;
  sln[r][c0 + 3] = (v2.w - mu2) * rs2 * gs.w;
  __syncthreads();

  float a10 = 0.f, a11 = 0.f, a12 = 0.f, a13 = 0.f;
  float a20 = 0.f, a21 = 0.f, a22 = 0.f, a23 = 0.f;
#pragma unroll 4
  for (int c = 0; c < CC; ++c) {
    float xv = sln[r][c];
    float4 w1 = *(const float4*)(Wg_ada + c * CC + c0);
    float4 w2 = *(const float4*)(W_skip + c * CC + c0);
    a10 = fmaf(xv, w1.x, a10); a11 = fmaf(xv, w1.y, a11);
    a12 = fmaf(xv, w1.z, a12); a13 = fmaf(xv, w1.w, a13);
    a20 = fmaf(xv, w2.x, a20); a21 = fmaf(xv, w2.y, a21);
    a22 = fmaf(xv, w2.z, a22); a23 = fmaf(xv, w2.w, a23);
  }
  float4 bga = *(const float4*)(bg_ada + c0);
  float ax = sigm(a10 + bga.x) * aln0 + a20;
  float ay = sigm(a11 + bga.y) * aln1 + a21;
  float az = sigm(a12 + bga.z) * aln2 + a22;
  float aw = sigm(a13 + bga.w) * aln3 + a23;
  as_[r][c0 + 0] = ax; as_[r][c0 + 1] = ay;
  as_[r][c0 + 2] = az; as_[r][c0 + 3] = aw;
  __syncthreads();

  const float* Ws[4]  = {Wq, Wk, Wv, Wg};
  float*       Os[4]  = {qb, kb, vb, gb};
#pragma unroll
  for (int m = 0; m < 4; ++m) {
    const float* W = Ws[m];
    float b0 = 0.f, b1 = 0.f, b2 = 0.f, b3 = 0.f;
#pragma unroll 4
    for (int c = 0; c < CC; ++c) {
      float xv = as_[r][c];
      float4 w = *(const float4*)(W + c * CC + c0);
      b0 = fmaf(xv, w.x, b0); b1 = fmaf(xv, w.y, b1);
      b2 = fmaf(xv, w.z, b2); b3 = fmaf(xv, w.w, b3);
    }
    float4 o;
    if (m == 0) {
      o.x = b0 * 0.25f; o.y = b1 * 0.25f; o.z = b2 * 0.25f; o.w = b3 * 0.25f;
    } else if (m == 3) {
      float4 bgv = *(const float4*)(bg + c0);
      o.x = sigm(b0 + bgv.x); o.y = sigm(b1 + bgv.y);
      o.z = sigm(b2 + bgv.z); o.w = sigm(b3 + bgv.w);
    } else {
      o.x = b0; o.y = b1; o.z = b2; o.w = b3;
    }
    *(float4*)(Os[m] + (size_t)row * CC + c0) = o;
  }
}

// ---------------------------------------------------------------------------
// K2: bias[w][h][q][k] = LN(pair[i, j, :])*gamma_p+beta_p @ W_pair  (only the
// needed 1/16 slice), -10000 where j out of range. 2048 blocks x 128 threads.
// ---------------------------------------------------------------------------
__global__ __launch_bounds__(128) void bias_kernel(
    const float* __restrict__ pair,
    const float* __restrict__ gamma_p, const float* __restrict__ beta_p,
    const float* __restrict__ W_pair,
    float* __restrict__ bias)
{
  __shared__ float wp[CPP * HH];
  __shared__ float gp[CPP];
  __shared__ float bp[CPP];
  const int tid = threadIdx.x;
  if (tid < CPP * HH) wp[tid] = W_pair[tid];
  if (tid < CPP) { gp[tid] = gamma_p[tid]; bp[tid] = beta_p[tid]; }
  __syncthreads();

  const int i  = blockIdx.x;      // token row 0..2047
  const int w  = i >> 5;
  const int qq = i & 31;
  const int k  = tid;             // 0..127
  const int j  = w * NQW + k - PADW;

  float bh[HH];
  if (j >= 0 && j < NTOK) {
    const float* p = pair + ((size_t)i * NTOK + j) * CPP;
    float x[CPP];
#pragma unroll
    for (int u = 0; u < CPP; u += 4) {
      float4 v = *(const float4*)(p + u);
      x[u] = v.x; x[u + 1] = v.y; x[u + 2] = v.z; x[u + 3] = v.w;
    }
    float s = 0.f;
#pragma unroll
    for (int c = 0; c < CPP; ++c) s += x[c];
    float mu = s * (1.0f / CPP);
    float vv = 0.f;
#pragma unroll
    for (int c = 0; c < CPP; ++c) { float d = x[c] - mu; vv = fmaf(d, d, vv); }
    float rs = rsqrtf(vv * (1.0f / CPP) + 1e-5f);
#pragma unroll
    for (int h = 0; h < HH; ++h) bh[h] = 0.f;
#pragma unroll
    for (int c = 0; c < CPP; ++c) {
      float y = (x[c] - mu) * rs * gp[c] + bp[c];
#pragma unroll
      for (int h = 0; h < HH; ++h) bh[h] = fmaf(y, wp[c * HH + h], bh[h]);
    }
  } else {
#pragma unroll
    for (int h = 0; h < HH; ++h) bh[h] = -10000.0f;
  }
#pragma unroll
  for (int h = 0; h < HH; ++h)
    bias[((size_t)((w * HH + h) * NQW + qq)) * NKW + k] = bh[h];
}

// ---------------------------------------------------------------------------
// K3: attention per (window, head). 512 blocks x 256 threads.
// logits = q.k + bias -> softmax(k) -> @v -> o_buf[row, h*16+d]
// ---------------------------------------------------------------------------
__global__ __launch_bounds__(256) void attn_kernel(
    const float* __restrict__ qb, const float* __restrict__ kb,
    const float* __restrict__ vb, const float* __restrict__ bias,
    float* __restrict__ ob)
{
  __shared__ float qs[NQW][20];
  __shared__ float ks[NKW][20];
  __shared__ float vs[NKW][20];
  __shared__ float att[NQW][132];
  const int w   = blockIdx.x >> 3;
  const int h   = blockIdx.x & 7;
  const int tid = threadIdx.x;

  if (tid < 128) {
    int qr = tid >> 2, c4 = (tid & 3) * 4;
    float4 v = *(const float4*)(qb + (size_t)(w * NQW + qr) * CC + h * DHH + c4);
    *(float4*)(&qs[qr][c4]) = v;
  }
#pragma unroll
  for (int it = 0; it < 2; ++it) {
    int idx = tid + it * 256;          // 0..511
    int kr = idx >> 2, c4 = (idx & 3) * 4;
    int j = w * NQW + kr - PADW;
    float4 kv = make_float4(0.f, 0.f, 0.f, 0.f);
    float4 vv = make_float4(0.f, 0.f, 0.f, 0.f);
    if (j >= 0 && j < NTOK) {
      kv = *(const float4*)(kb + (size_t)j * CC + h * DHH + c4);
      vv = *(const float4*)(vb + (size_t)j * CC + h * DHH + c4);
    }
    *(float4*)(&ks[kr][c4]) = kv;
    *(float4*)(&vs[kr][c4]) = vv;
  }
  const float* bt = bias + (size_t)(w * HH + h) * NQW * NKW;
#pragma unroll
  for (int it = 0; it < 4; ++it) {
    int idx = tid + it * 256;          // 0..1023 float4 units
    int qr = idx >> 5, k4 = (idx & 31) * 4;
    float4 bv = *(const float4*)(bt + qr * NKW + k4);
    *(float4*)(&att[qr][k4]) = bv;
  }
  __syncthreads();

  const int qq = tid >> 3;   // 0..31
  const int t  = tid & 7;    // 0..7
  float4 q0 = *(float4*)(&qs[qq][0]);
  float4 q1 = *(float4*)(&qs[qq][4]);
  float4 q2 = *(float4*)(&qs[qq][8]);
  float4 q3 = *(float4*)(&qs[qq][12]);

  float l[16];
#pragma unroll
  for (int i = 0; i < 16; ++i) {
    int k = t + 8 * i;
    const float* kr = &ks[k][0];
    float4 k0 = *(const float4*)(kr);
    float4 k1 = *(const float4*)(kr + 4);
    float4 k2 = *(const float4*)(kr + 8);
    float4 k3 = *(const float4*)(kr + 12);
    float d = 0.f;
    d = fmaf(q0.x, k0.x, d); d = fmaf(q0.y, k0.y, d);
    d = fmaf(q0.z, k0.z, d); d = fmaf(q0.w, k0.w, d);
    d = fmaf(q1.x, k1.x, d); d = fmaf(q1.y, k1.y, d);
    d = fmaf(q1.z, k1.z, d); d = fmaf(q1.w, k1.w, d);
    d = fmaf(q2.x, k2.x, d); d = fmaf(q2.y, k2.y, d);
    d = fmaf(q2.z, k2.z, d); d = fmaf(q2.w, k2.w, d);
    d = fmaf(q3.x, k3.x, d); d = fmaf(q3.y, k3.y, d);
    d = fmaf(q3.z, k3.z, d); d = fmaf(q3.w, k3.w, d);
    l[i] = att[qq][k] + d;
  }
  float m = l[0];
#pragma unroll
  for (int i = 1; i < 16; ++i) m = fmaxf(m, l[i]);
  m = fmaxf(m, __shfl_xor(m, 1));
  m = fmaxf(m, __shfl_xor(m, 2));
  m = fmaxf(m, __shfl_xor(m, 4));
  float s = 0.f;
  float p[16];
#pragma unroll
  for (int i = 0; i < 16; ++i) { p[i] = expf(l[i] - m); s += p[i]; }
  s += __shfl_xor(s, 1);
  s += __shfl_xor(s, 2);
  s += __shfl_xor(s, 4);
  float inv = 1.0f / s;
#pragma unroll
  for (int i = 0; i < 16; ++i) att[qq][t + 8 * i] = p[i] * inv;
  __syncthreads();

  const int d0 = t * 2;
  float a0 = 0.f, a1 = 0.f;
#pragma unroll 8
  for (int k = 0; k < NKW; ++k) {
    float a = att[qq][k];
    float2 vv = *(float2*)(&vs[k][d0]);
    a0 = fmaf(a, vv.x, a0);
    a1 = fmaf(a, vv.y, a1);
  }
  float2 o2; o2.x = a0; o2.y = a1;
  *(float2*)(ob + (size_t)(w * NQW + qq) * CC + h * DHH + d0) = o2;
}

// ---------------------------------------------------------------------------
// K4: u = (o*g)@Wo + bo ; out = sigmoid(u@W_out + b_out) * u
// block: 8 rows x 256 threads
// ---------------------------------------------------------------------------
__global__ __launch_bounds__(256) void out_kernel(
    const float* __restrict__ ob, const float* __restrict__ gb,
    const float* __restrict__ Wo, const float* __restrict__ bo,
    const float* __restrict__ W_out, const float* __restrict__ b_out,
    float* __restrict__ out)
{
  __shared__ float og[8][132];
  __shared__ float us[8][132];
  const int tid = threadIdx.x;
  const int r   = tid >> 5;
  const int t   = tid & 31;
  const int row = blockIdx.x * 8 + r;
  const int c0  = t * 4;

  float4 o4 = *(const float4*)(ob + (size_t)row * CC + c0);
  float4 g4 = *(const float4*)(gb + (size_t)row * CC + c0);
  og[r][c0 + 0] = o4.x * g4.x;
  og[r][c0 + 1] = o4.y * g4.y;
  og[r][c0 + 2] = o4.z * g4.z;
  og[r][c0 + 3] = o4.w * g4.w;
  __syncthreads();

  float u0 = 0.f, u1 = 0.f, u2 = 0.f, u3 = 0.f;
#pragma unroll 4
  for (int c = 0; c < CC; ++c) {
    float xv = og[r][c];
    float4 w = *(const float4*)(Wo + c * CC + c0);
    u0 = fmaf(xv, w.x, u0); u1 = fmaf(xv, w.y, u1);
    u2 = fmaf(xv, w.z, u2); u3 = fmaf(xv, w.w, u3);
  }
  float4 bov = *(const float4*)(bo + c0);
  u0 += bov.x; u1 += bov.y; u2 += bov.z; u3 += bov.w;
  us[r][c0 + 0] = u0; us[r][c0 + 1] = u1;
  us[r][c0 + 2] = u2; us[r][c0 + 3] = u3;
  __syncthreads();

  float r0 = 0.f, r1 = 0.f, r2 = 0.f, r3 = 0.f;
#pragma unroll 4
  for (int c = 0; c < CC; ++c) {
    float xv = us[r][c];
    float4 w = *(const float4*)(W_out + c * CC + c0);
    r0 = fmaf(xv, w.x, r0); r1 = fmaf(xv, w.y, r1);
    r2 = fmaf(xv, w.z, r2); r3 = fmaf(xv, w.w, r3);
  }
  float4 bov2 = *(const float4*)(b_out + c0);
  float4 res;
  res.x = sigm(r0 + bov2.x) * u0;
  res.y = sigm(r1 + bov2.y) * u1;
  res.z = sigm(r2 + bov2.z) * u2;
  res.w = sigm(r3 + bov2.w) * u3;
  *(float4*)(out + (size_t)row * CC + c0) = res;
}

// ---------------------------------------------------------------------------
extern "C" void kernel_launch(void* const* d_in, const int* in_sizes, int n_in,
                              void* d_out, int out_size, void* d_ws, size_t ws_size,
                              hipStream_t stream) {
  (void)in_sizes; (void)n_in; (void)out_size; (void)ws_size;
  const float* x1      = (const float*)d_in[0];
  const float* x2      = (const float*)d_in[1];
  const float* pair    = (const float*)d_in[2];
  const float* gamma_s = (const float*)d_in[3];
  const float* Wg_ada  = (const float*)d_in[4];
  const float* bg_ada  = (const float*)d_in[5];
  const float* W_skip  = (const float*)d_in[6];
  const float* gamma_p = (const float*)d_in[7];
  const float* beta_p  = (const float*)d_in[8];
  const float* W_pair  = (const float*)d_in[9];
  const float* Wq      = (const float*)d_in[10];
  const float* Wk      = (const float*)d_in[11];
  const float* Wv      = (const float*)d_in[12];
  const float* Wg      = (const float*)d_in[13];
  const float* bg      = (const float*)d_in[14];
  const float* Wo      = (const float*)d_in[15];
  const float* bo      = (const float*)d_in[16];
  const float* W_out   = (const float*)d_in[17];
  const float* b_out   = (const float*)d_in[18];

  float* ws   = (float*)d_ws;
  const size_t NC = (size_t)NTOK * CC;   // 262144
  float* qb   = ws;
  float* kb   = ws + NC;
  float* vb   = ws + 2 * NC;
  float* gb   = ws + 3 * NC;
  float* obuf = ws + 4 * NC;
  float* bias = ws + 5 * NC;             // 64*8*32*128 = 2097152 floats

  prep_kernel<<<NTOK / 8, 256, 0, stream>>>(x1, x2, gamma_s, Wg_ada, bg_ada,
                                            W_skip, Wq, Wk, Wv, Wg, bg,
                                            qb, kb, vb, gb);
  bias_kernel<<<NTOK, 128, 0, stream>>>(pair, gamma_p, beta_p, W_pair, bias);
  attn_kernel<<<NBW * HH, 256, 0, stream>>>(qb, kb, vb, bias, obuf);
  out_kernel<<<NTOK / 8, 256, 0, stream>>>(obuf, gb, Wo, bo, W_out, b_out,
                                           (float*)d_out);
}

// Round 2
// 88.663 us; speedup vs baseline: 1.0293x; 1.0293x over previous
//
#include <hip/hip_runtime.h>
#include <math.h>

#define NTOK 2048
#define CC   128
#define CPP  16
#define HH   8
#define DHH  16
#define NQW  32
#define NKW  128
#define PADW 48
#define NBW  64

__device__ __forceinline__ float sigm(float x) { return 1.0f / (1.0f + expf(-x)); }

// ---------------------------------------------------------------------------
// K1 fused: blocks [0,512): prep role  (rowtile = b>>1, matrix-pair = b&1)
//           blocks [512,1024): bias role (4 tokens per block)
// 512 threads each.
// prep: LN(x1), LN(x2)*gamma_s, a = sigmoid(sln@Wg_ada+bg_ada)*aln + sln@W_skip
//       then pair {q=(a@Wq)*0.25, k=a@Wk} or {v=a@Wv, g=sigmoid(a@Wg+bg)}
// bias: bias[w][h][q][k] = (LN(pair[i,j,:])*gamma_p+beta_p) @ W_pair, j OOB -> -1e4
// ---------------------------------------------------------------------------
__global__ __launch_bounds__(512) void fused1_kernel(
    const float* __restrict__ x1, const float* __restrict__ x2,
    const float* __restrict__ gamma_s,
    const float* __restrict__ Wg_ada, const float* __restrict__ bg_ada,
    const float* __restrict__ W_skip,
    const float* __restrict__ Wq, const float* __restrict__ Wk,
    const float* __restrict__ Wv, const float* __restrict__ Wg,
    const float* __restrict__ bg,
    const float* __restrict__ pair,
    const float* __restrict__ gamma_p, const float* __restrict__ beta_p,
    const float* __restrict__ W_pair,
    float* __restrict__ qb, float* __restrict__ kb,
    float* __restrict__ vb, float* __restrict__ gb,
    float* __restrict__ bias)
{
  const int b   = blockIdx.x;
  const int tid = threadIdx.x;

  if (b < 512) {
    __shared__ float sln[8][130];
    __shared__ float as_[8][130];
    const int rt  = b >> 1;
    const int m2  = b & 1;
    const int r   = tid >> 6;     // 0..7 (one row per wave)
    const int t   = tid & 63;
    const int row = rt * 8 + r;
    const int c0  = t * 2;

    float2 v1 = *(const float2*)(x1 + (size_t)row * CC + c0);
    float2 v2 = *(const float2*)(x2 + (size_t)row * CC + c0);
    float s1 = v1.x + v1.y, p1 = v1.x * v1.x + v1.y * v1.y;
    float s2 = v2.x + v2.y, p2 = v2.x * v2.x + v2.y * v2.y;
#pragma unroll
    for (int m = 1; m < 64; m <<= 1) {
      s1 += __shfl_xor(s1, m); p1 += __shfl_xor(p1, m);
      s2 += __shfl_xor(s2, m); p2 += __shfl_xor(p2, m);
    }
    const float rc = 1.0f / 128.0f;
    float mu1 = s1 * rc, mu2 = s2 * rc;
    float rs1 = rsqrtf(p1 * rc - mu1 * mu1 + 1e-5f);
    float rs2 = rsqrtf(p2 * rc - mu2 * mu2 + 1e-5f);
    float2 gs = *(const float2*)(gamma_s + c0);
    float aln0 = (v1.x - mu1) * rs1;
    float aln1 = (v1.y - mu1) * rs1;
    sln[r][c0]     = (v2.x - mu2) * rs2 * gs.x;
    sln[r][c0 + 1] = (v2.y - mu2) * rs2 * gs.y;
    __syncthreads();

    // stage 1: adaLN gate + skip (8 independent FMA chains)
    float aa0 = 0.f, aa1 = 0.f, aa2 = 0.f, aa3 = 0.f;
    float ss0 = 0.f, ss1 = 0.f, ss2 = 0.f, ss3 = 0.f;
#pragma unroll 2
    for (int c = 0; c < CC; c += 2) {
      float xe = sln[r][c], xo = sln[r][c + 1];
      float2 we = *(const float2*)(Wg_ada + c * CC + c0);
      float2 wo = *(const float2*)(Wg_ada + (c + 1) * CC + c0);
      float2 ke = *(const float2*)(W_skip + c * CC + c0);
      float2 ko = *(const float2*)(W_skip + (c + 1) * CC + c0);
      aa0 = fmaf(xe, we.x, aa0); aa1 = fmaf(xe, we.y, aa1);
      aa2 = fmaf(xo, wo.x, aa2); aa3 = fmaf(xo, wo.y, aa3);
      ss0 = fmaf(xe, ke.x, ss0); ss1 = fmaf(xe, ke.y, ss1);
      ss2 = fmaf(xo, ko.x, ss2); ss3 = fmaf(xo, ko.y, ss3);
    }
    float2 bga = *(const float2*)(bg_ada + c0);
    float a0 = sigm(aa0 + aa2 + bga.x) * aln0 + ss0 + ss2;
    float a1 = sigm(aa1 + aa3 + bga.y) * aln1 + ss1 + ss3;
    as_[r][c0]     = a0;
    as_[r][c0 + 1] = a1;
    __syncthreads();

    // stage 2: two projection matrices for this block's pair
    const float* WA = m2 ? Wv : Wq;
    const float* WB = m2 ? Wg : Wk;
    float pa0 = 0.f, pa1 = 0.f, pa2 = 0.f, pa3 = 0.f;
    float pb0 = 0.f, pb1 = 0.f, pb2 = 0.f, pb3 = 0.f;
#pragma unroll 2
    for (int c = 0; c < CC; c += 2) {
      float xe = as_[r][c], xo = as_[r][c + 1];
      float2 we = *(const float2*)(WA + c * CC + c0);
      float2 wo = *(const float2*)(WA + (c + 1) * CC + c0);
      float2 ke = *(const float2*)(WB + c * CC + c0);
      float2 ko = *(const float2*)(WB + (c + 1) * CC + c0);
      pa0 = fmaf(xe, we.x, pa0); pa1 = fmaf(xe, we.y, pa1);
      pa2 = fmaf(xo, wo.x, pa2); pa3 = fmaf(xo, wo.y, pa3);
      pb0 = fmaf(xe, ke.x, pb0); pb1 = fmaf(xe, ke.y, pb1);
      pb2 = fmaf(xo, ko.x, pb2); pb3 = fmaf(xo, ko.y, pb3);
    }
    float A0 = pa0 + pa2, A1 = pa1 + pa3;
    float B0 = pb0 + pb2, B1 = pb1 + pb3;
    const size_t off = (size_t)row * CC + c0;
    if (m2 == 0) {
      float2 qv; qv.x = A0 * 0.25f; qv.y = A1 * 0.25f;
      float2 kv; kv.x = B0;         kv.y = B1;
      *(float2*)(qb + off) = qv;
      *(float2*)(kb + off) = kv;
    } else {
      float2 bgv = *(const float2*)(bg + c0);
      float2 vv; vv.x = A0; vv.y = A1;
      float2 gv; gv.x = sigm(B0 + bgv.x); gv.y = sigm(B1 + bgv.y);
      *(float2*)(vb + off) = vv;
      *(float2*)(gb + off) = gv;
    }
  } else {
    __shared__ float wp[CPP * HH];
    __shared__ float gp[CPP];
    __shared__ float bp[CPP];
    if (tid < CPP * HH) wp[tid] = W_pair[tid];
    if (tid < CPP) { gp[tid] = gamma_p[tid]; bp[tid] = beta_p[tid]; }
    __syncthreads();

    const int i  = (b - 512) * 4 + (tid >> 7);   // token 0..2047
    const int w  = i >> 5;
    const int qq = i & 31;
    const int k  = tid & 127;
    const int j  = w * NQW + k - PADW;

    float bh[HH];
    if (j >= 0 && j < NTOK) {
      const float* p = pair + ((size_t)i * NTOK + j) * CPP;
      float x[CPP];
#pragma unroll
      for (int u = 0; u < CPP; u += 4) {
        float4 v = *(const float4*)(p + u);
        x[u] = v.x; x[u + 1] = v.y; x[u + 2] = v.z; x[u + 3] = v.w;
      }
      float s = 0.f;
#pragma unroll
      for (int c = 0; c < CPP; ++c) s += x[c];
      float mu = s * (1.0f / CPP);
      float vv = 0.f;
#pragma unroll
      for (int c = 0; c < CPP; ++c) { float d = x[c] - mu; vv = fmaf(d, d, vv); }
      float rs = rsqrtf(vv * (1.0f / CPP) + 1e-5f);
#pragma unroll
      for (int h = 0; h < HH; ++h) bh[h] = 0.f;
#pragma unroll
      for (int c = 0; c < CPP; ++c) {
        float y = (x[c] - mu) * rs * gp[c] + bp[c];
#pragma unroll
        for (int h = 0; h < HH; ++h) bh[h] = fmaf(y, wp[c * HH + h], bh[h]);
      }
    } else {
#pragma unroll
      for (int h = 0; h < HH; ++h) bh[h] = -10000.0f;
    }
#pragma unroll
    for (int h = 0; h < HH; ++h)
      bias[((size_t)((w * HH + h) * NQW + qq)) * NKW + k] = bh[h];
  }
}

// ---------------------------------------------------------------------------
// K2: attention per (window, head). 512 blocks x 256 threads.
// thread = (qg 0..15, t 0..15): owns q-rows {2qg,2qg+1}, k-cols {t+16*i}.
// probabilities stay in registers; PV is outer-product + 16-lane shfl reduce.
// ---------------------------------------------------------------------------
__global__ __launch_bounds__(256) void attn_kernel(
    const float* __restrict__ qb, const float* __restrict__ kb,
    const float* __restrict__ vb, const float* __restrict__ bias,
    float* __restrict__ ob)
{
  __shared__ float qs[NQW][20];
  __shared__ float ks[NKW][20];
  __shared__ float vs[NKW][20];
  __shared__ float bs[NQW][132];
  const int w   = blockIdx.x >> 3;
  const int h   = blockIdx.x & 7;
  const int tid = threadIdx.x;

  if (tid < 128) {
    int qr = tid >> 2, c4 = (tid & 3) * 4;
    float4 v = *(const float4*)(qb + (size_t)(w * NQW + qr) * CC + h * DHH + c4);
    *(float4*)(&qs[qr][c4]) = v;
  }
#pragma unroll
  for (int it = 0; it < 2; ++it) {
    int idx = tid + it * 256;          // 0..511
    int kr = idx >> 2, c4 = (idx & 3) * 4;
    int j = w * NQW + kr - PADW;
    float4 kv = make_float4(0.f, 0.f, 0.f, 0.f);
    float4 vv = make_float4(0.f, 0.f, 0.f, 0.f);
    if (j >= 0 && j < NTOK) {
      kv = *(const float4*)(kb + (size_t)j * CC + h * DHH + c4);
      vv = *(const float4*)(vb + (size_t)j * CC + h * DHH + c4);
    }
    *(float4*)(&ks[kr][c4]) = kv;
    *(float4*)(&vs[kr][c4]) = vv;
  }
  const float* bt = bias + (size_t)(w * HH + h) * NQW * NKW;
#pragma unroll
  for (int it = 0; it < 4; ++it) {
    int idx = tid + it * 256;          // 0..1023 float4 units
    int qr = idx >> 5, k4 = (idx & 31) * 4;
    float4 bv = *(const float4*)(bt + qr * NKW + k4);
    *(float4*)(&bs[qr][k4]) = bv;
  }
  __syncthreads();

  const int qg = tid >> 4;   // 0..15
  const int t  = tid & 15;   // 0..15
  const int r0 = qg * 2, r1 = r0 + 1;

  float4 qa0 = *(float4*)(&qs[r0][0]);
  float4 qa1 = *(float4*)(&qs[r0][4]);
  float4 qa2 = *(float4*)(&qs[r0][8]);
  float4 qa3 = *(float4*)(&qs[r0][12]);
  float4 qb0 = *(float4*)(&qs[r1][0]);
  float4 qb1 = *(float4*)(&qs[r1][4]);
  float4 qb2 = *(float4*)(&qs[r1][8]);
  float4 qb3 = *(float4*)(&qs[r1][12]);

  float l0[8], l1[8];
#pragma unroll
  for (int i = 0; i < 8; ++i) {
    int k = t + 16 * i;
    const float* kr = &ks[k][0];
    float4 k0 = *(const float4*)(kr);
    float4 k1 = *(const float4*)(kr + 4);
    float4 k2 = *(const float4*)(kr + 8);
    float4 k3 = *(const float4*)(kr + 12);
    float da = 0.f, db = 0.f;
    da = fmaf(qa0.x, k0.x, da); da = fmaf(qa0.y, k0.y, da);
    da = fmaf(qa0.z, k0.z, da); da = fmaf(qa0.w, k0.w, da);
    da = fmaf(qa1.x, k1.x, da); da = fmaf(qa1.y, k1.y, da);
    da = fmaf(qa1.z, k1.z, da); da = fmaf(qa1.w, k1.w, da);
    da = fmaf(qa2.x, k2.x, da); da = fmaf(qa2.y, k2.y, da);
    da = fmaf(qa2.z, k2.z, da); da = fmaf(qa2.w, k2.w, da);
    da = fmaf(qa3.x, k3.x, da); da = fmaf(qa3.y, k3.y, da);
    da = fmaf(qa3.z, k3.z, da); da = fmaf(qa3.w, k3.w, da);
    db = fmaf(qb0.x, k0.x, db); db = fmaf(qb0.y, k0.y, db);
    db = fmaf(qb0.z, k0.z, db); db = fmaf(qb0.w, k0.w, db);
    db = fmaf(qb1.x, k1.x, db); db = fmaf(qb1.y, k1.y, db);
    db = fmaf(qb1.z, k1.z, db); db = fmaf(qb1.w, k1.w, db);
    db = fmaf(qb2.x, k2.x, db); db = fmaf(qb2.y, k2.y, db);
    db = fmaf(qb2.z, k2.z, db); db = fmaf(qb2.w, k2.w, db);
    db = fmaf(qb3.x, k3.x, db); db = fmaf(qb3.y, k3.y, db);
    db = fmaf(qb3.z, k3.z, db); db = fmaf(qb3.w, k3.w, db);
    l0[i] = db * 0.f + da + bs[r0][k];   // keep order simple
    l1[i] = db + bs[r1][k];
  }

  float m0 = l0[0], m1 = l1[0];
#pragma unroll
  for (int i = 1; i < 8; ++i) { m0 = fmaxf(m0, l0[i]); m1 = fmaxf(m1, l1[i]); }
#pragma unroll
  for (int m = 1; m < 16; m <<= 1) {
    m0 = fmaxf(m0, __shfl_xor(m0, m));
    m1 = fmaxf(m1, __shfl_xor(m1, m));
  }
  float s0 = 0.f, s1 = 0.f;
  float p0[8], p1[8];
#pragma unroll
  for (int i = 0; i < 8; ++i) {
    p0[i] = expf(l0[i] - m0); s0 += p0[i];
    p1[i] = expf(l1[i] - m1); s1 += p1[i];
  }
#pragma unroll
  for (int m = 1; m < 16; m <<= 1) {
    s0 += __shfl_xor(s0, m);
    s1 += __shfl_xor(s1, m);
  }
  float inv0 = 1.0f / s0, inv1 = 1.0f / s1;
#pragma unroll
  for (int i = 0; i < 8; ++i) { p0[i] *= inv0; p1[i] *= inv1; }

  float o0[16], o1[16];
#pragma unroll
  for (int d = 0; d < 16; ++d) { o0[d] = 0.f; o1[d] = 0.f; }
#pragma unroll
  for (int i = 0; i < 8; ++i) {
    int k = t + 16 * i;
    const float* vr = &vs[k][0];
    float4 v0 = *(const float4*)(vr);
    float4 v1 = *(const float4*)(vr + 4);
    float4 v2 = *(const float4*)(vr + 8);
    float4 v3 = *(const float4*)(vr + 12);
    float pa = p0[i], pb = p1[i];
    o0[0]  = fmaf(pa, v0.x, o0[0]);  o0[1]  = fmaf(pa, v0.y, o0[1]);
    o0[2]  = fmaf(pa, v0.z, o0[2]);  o0[3]  = fmaf(pa, v0.w, o0[3]);
    o0[4]  = fmaf(pa, v1.x, o0[4]);  o0[5]  = fmaf(pa, v1.y, o0[5]);
    o0[6]  = fmaf(pa, v1.z, o0[6]);  o0[7]  = fmaf(pa, v1.w, o0[7]);
    o0[8]  = fmaf(pa, v2.x, o0[8]);  o0[9]  = fmaf(pa, v2.y, o0[9]);
    o0[10] = fmaf(pa, v2.z, o0[10]); o0[11] = fmaf(pa, v2.w, o0[11]);
    o0[12] = fmaf(pa, v3.x, o0[12]); o0[13] = fmaf(pa, v3.y, o0[13]);
    o0[14] = fmaf(pa, v3.z, o0[14]); o0[15] = fmaf(pa, v3.w, o0[15]);
    o1[0]  = fmaf(pb, v0.x, o1[0]);  o1[1]  = fmaf(pb, v0.y, o1[1]);
    o1[2]  = fmaf(pb, v0.z, o1[2]);  o1[3]  = fmaf(pb, v0.w, o1[3]);
    o1[4]  = fmaf(pb, v1.x, o1[4]);  o1[5]  = fmaf(pb, v1.y, o1[5]);
    o1[6]  = fmaf(pb, v1.z, o1[6]);  o1[7]  = fmaf(pb, v1.w, o1[7]);
    o1[8]  = fmaf(pb, v2.x, o1[8]);  o1[9]  = fmaf(pb, v2.y, o1[9]);
    o1[10] = fmaf(pb, v2.z, o1[10]); o1[11] = fmaf(pb, v2.w, o1[11]);
    o1[12] = fmaf(pb, v3.x, o1[12]); o1[13] = fmaf(pb, v3.y, o1[13]);
    o1[14] = fmaf(pb, v3.z, o1[14]); o1[15] = fmaf(pb, v3.w, o1[15]);
  }
#pragma unroll
  for (int d = 0; d < 16; ++d) {
#pragma unroll
    for (int m = 1; m < 16; m <<= 1) {
      o0[d] += __shfl_xor(o0[d], m);
      o1[d] += __shfl_xor(o1[d], m);
    }
  }
  // lane t takes element d==t (unrolled select, no runtime reg indexing)
  float w0 = 0.f, w1 = 0.f;
#pragma unroll
  for (int d = 0; d < 16; ++d) {
    w0 = (t == d) ? o0[d] : w0;
    w1 = (t == d) ? o1[d] : w1;
  }
  ob[(size_t)(w * NQW + r0) * CC + h * DHH + t] = w0;
  ob[(size_t)(w * NQW + r1) * CC + h * DHH + t] = w1;
}

// ---------------------------------------------------------------------------
// K3: u = (o*g)@Wo + bo ; out = sigmoid(u@W_out + b_out) * u
// 512 blocks x 512 threads: 4 rows x 128 cols, 1 col/thread.
// ---------------------------------------------------------------------------
__global__ __launch_bounds__(512) void out_kernel(
    const float* __restrict__ ob_, const float* __restrict__ gb_,
    const float* __restrict__ Wo, const float* __restrict__ bo,
    const float* __restrict__ W_out, const float* __restrict__ b_out,
    float* __restrict__ out)
{
  __shared__ float og[4][132];
  __shared__ float us[4][132];
  const int tid = threadIdx.x;
  const int r   = tid >> 7;       // 0..3
  const int col = tid & 127;
  const int row = blockIdx.x * 4 + r;

  float ov = ob_[(size_t)row * CC + col];
  float gv = gb_[(size_t)row * CC + col];
  og[r][col] = ov * gv;
  __syncthreads();

  float u0 = 0.f, u1 = 0.f;
#pragma unroll 4
  for (int c = 0; c < CC; c += 2) {
    u0 = fmaf(og[r][c],     Wo[c * CC + col],       u0);
    u1 = fmaf(og[r][c + 1], Wo[(c + 1) * CC + col], u1);
  }
  float u = u0 + u1 + bo[col];
  us[r][col] = u;
  __syncthreads();

  float a0 = 0.f, a1 = 0.f;
#pragma unroll 4
  for (int c = 0; c < CC; c += 2) {
    a0 = fmaf(us[r][c],     W_out[c * CC + col],       a0);
    a1 = fmaf(us[r][c + 1], W_out[(c + 1) * CC + col], a1);
  }
  out[(size_t)row * CC + col] = sigm(a0 + a1 + b_out[col]) * u;
}

// ---------------------------------------------------------------------------
extern "C" void kernel_launch(void* const* d_in, const int* in_sizes, int n_in,
                              void* d_out, int out_size, void* d_ws, size_t ws_size,
                              hipStream_t stream) {
  (void)in_sizes; (void)n_in; (void)out_size; (void)ws_size;
  const float* x1      = (const float*)d_in[0];
  const float* x2      = (const float*)d_in[1];
  const float* pair    = (const float*)d_in[2];
  const float* gamma_s = (const float*)d_in[3];
  const float* Wg_ada  = (const float*)d_in[4];
  const float* bg_ada  = (const float*)d_in[5];
  const float* W_skip  = (const float*)d_in[6];
  const float* gamma_p = (const float*)d_in[7];
  const float* beta_p  = (const float*)d_in[8];
  const float* W_pair  = (const float*)d_in[9];
  const float* Wq      = (const float*)d_in[10];
  const float* Wk      = (const float*)d_in[11];
  const float* Wv      = (const float*)d_in[12];
  const float* Wg      = (const float*)d_in[13];
  const float* bg      = (const float*)d_in[14];
  const float* Wo      = (const float*)d_in[15];
  const float* bo      = (const float*)d_in[16];
  const float* W_out   = (const float*)d_in[17];
  const float* b_out   = (const float*)d_in[18];

  float* ws   = (float*)d_ws;
  const size_t NC = (size_t)NTOK * CC;   // 262144
  float* qb   = ws;
  float* kb   = ws + NC;
  float* vb   = ws + 2 * NC;
  float* gb   = ws + 3 * NC;
  float* obuf = ws + 4 * NC;
  float* bias = ws + 5 * NC;             // 64*8*32*128 = 2097152 floats

  fused1_kernel<<<1024, 512, 0, stream>>>(x1, x2, gamma_s, Wg_ada, bg_ada,
                                          W_skip, Wq, Wk, Wv, Wg, bg,
                                          pair, gamma_p, beta_p, W_pair,
                                          qb, kb, vb, gb, bias);
  attn_kernel<<<NBW * HH, 256, 0, stream>>>(qb, kb, vb, bias, obuf);
  out_kernel<<<NTOK / 4, 512, 0, stream>>>(obuf, gb, Wo, bo, W_out, b_out,
                                           (float*)d_out);
}

// Round 3
// 70.064 us; speedup vs baseline: 1.3025x; 1.2655x over previous
//
#include <hip/hip_runtime.h>
#include <math.h>

#define NTOK 2048
#define CC   128
#define CPP  16
#define HH   8
#define DHH  16
#define NQW  32
#define NKW  128
#define PADW 48
#define NBW  64

__device__ __forceinline__ float sigm(float x) { return 1.0f / (1.0f + expf(-x)); }

// ---------------------------------------------------------------------------
// K1 fused: blocks [0,256): prep role.  16 rows/block, pair-split (b&1).
//   thread: g=tid>>5 (row in tile), t=tid&31, c0=t*4 (float4 cols).
//   wave = 2 rows x 32 lanes -> duplicate W addresses merge; each wave streams
//   W once per 2 rows (was: once per row with float2) -> 4x fewer W-instrs.
// blocks [256,768): bias role (4 tokens per block).
// ---------------------------------------------------------------------------
__global__ __launch_bounds__(512) void fused1_kernel(
    const float* __restrict__ x1, const float* __restrict__ x2,
    const float* __restrict__ gamma_s,
    const float* __restrict__ Wg_ada, const float* __restrict__ bg_ada,
    const float* __restrict__ W_skip,
    const float* __restrict__ Wq, const float* __restrict__ Wk,
    const float* __restrict__ Wv, const float* __restrict__ Wg,
    const float* __restrict__ bg,
    const float* __restrict__ pair,
    const float* __restrict__ gamma_p, const float* __restrict__ beta_p,
    const float* __restrict__ W_pair,
    float* __restrict__ qb, float* __restrict__ kb,
    float* __restrict__ vb, float* __restrict__ gb,
    float* __restrict__ bias)
{
  const int b   = blockIdx.x;
  const int tid = threadIdx.x;

  if (b < 256) {
    __shared__ float sln[16][132];
    __shared__ float as_[16][132];
    const int rt  = b >> 1;
    const int m2  = b & 1;
    const int g   = tid >> 5;       // 0..15 row in tile
    const int t   = tid & 31;
    const int row = rt * 16 + g;
    const int c0  = t * 4;

    float4 v1 = *(const float4*)(x1 + (size_t)row * CC + c0);
    float4 v2 = *(const float4*)(x2 + (size_t)row * CC + c0);
    float s1 = v1.x + v1.y + v1.z + v1.w;
    float p1 = v1.x * v1.x + v1.y * v1.y + v1.z * v1.z + v1.w * v1.w;
    float s2 = v2.x + v2.y + v2.z + v2.w;
    float p2 = v2.x * v2.x + v2.y * v2.y + v2.z * v2.z + v2.w * v2.w;
#pragma unroll
    for (int m = 1; m < 32; m <<= 1) {   // reduce within 32-lane half-wave = one row
      s1 += __shfl_xor(s1, m); p1 += __shfl_xor(p1, m);
      s2 += __shfl_xor(s2, m); p2 += __shfl_xor(p2, m);
    }
    const float rc = 1.0f / 128.0f;
    float mu1 = s1 * rc, mu2 = s2 * rc;
    float rs1 = rsqrtf(p1 * rc - mu1 * mu1 + 1e-5f);
    float rs2 = rsqrtf(p2 * rc - mu2 * mu2 + 1e-5f);
    float4 gs = *(const float4*)(gamma_s + c0);
    float aln0 = (v1.x - mu1) * rs1;
    float aln1 = (v1.y - mu1) * rs1;
    float aln2 = (v1.z - mu1) * rs1;
    float aln3 = (v1.w - mu1) * rs1;
    sln[g][c0]     = (v2.x - mu2) * rs2 * gs.x;
    sln[g][c0 + 1] = (v2.y - mu2) * rs2 * gs.y;
    sln[g][c0 + 2] = (v2.z - mu2) * rs2 * gs.z;
    sln[g][c0 + 3] = (v2.w - mu2) * rs2 * gs.w;
    __syncthreads();

    // stage 1: adaLN gate + skip
    float ga0 = 0.f, ga1 = 0.f, ga2 = 0.f, ga3 = 0.f;
    float sk0 = 0.f, sk1 = 0.f, sk2 = 0.f, sk3 = 0.f;
#pragma unroll 4
    for (int c = 0; c < CC; ++c) {
      float xv = sln[g][c];
      float4 wg4 = *(const float4*)(Wg_ada + c * CC + c0);
      float4 ws4 = *(const float4*)(W_skip + c * CC + c0);
      ga0 = fmaf(xv, wg4.x, ga0); ga1 = fmaf(xv, wg4.y, ga1);
      ga2 = fmaf(xv, wg4.z, ga2); ga3 = fmaf(xv, wg4.w, ga3);
      sk0 = fmaf(xv, ws4.x, sk0); sk1 = fmaf(xv, ws4.y, sk1);
      sk2 = fmaf(xv, ws4.z, sk2); sk3 = fmaf(xv, ws4.w, sk3);
    }
    float4 bga = *(const float4*)(bg_ada + c0);
    float a0 = sigm(ga0 + bga.x) * aln0 + sk0;
    float a1 = sigm(ga1 + bga.y) * aln1 + sk1;
    float a2 = sigm(ga2 + bga.z) * aln2 + sk2;
    float a3 = sigm(ga3 + bga.w) * aln3 + sk3;
    as_[g][c0]     = a0;
    as_[g][c0 + 1] = a1;
    as_[g][c0 + 2] = a2;
    as_[g][c0 + 3] = a3;
    __syncthreads();

    // stage 2: two projection matrices for this block's pair
    const float* WA = m2 ? Wv : Wq;
    const float* WB = m2 ? Wg : Wk;
    float A0 = 0.f, A1 = 0.f, A2 = 0.f, A3 = 0.f;
    float B0 = 0.f, B1 = 0.f, B2 = 0.f, B3 = 0.f;
#pragma unroll 4
    for (int c = 0; c < CC; ++c) {
      float xv = as_[g][c];
      float4 wa = *(const float4*)(WA + c * CC + c0);
      float4 wb = *(const float4*)(WB + c * CC + c0);
      A0 = fmaf(xv, wa.x, A0); A1 = fmaf(xv, wa.y, A1);
      A2 = fmaf(xv, wa.z, A2); A3 = fmaf(xv, wa.w, A3);
      B0 = fmaf(xv, wb.x, B0); B1 = fmaf(xv, wb.y, B1);
      B2 = fmaf(xv, wb.z, B2); B3 = fmaf(xv, wb.w, B3);
    }
    const size_t off = (size_t)row * CC + c0;
    if (m2 == 0) {
      float4 qv; qv.x = A0 * 0.25f; qv.y = A1 * 0.25f;
      qv.z = A2 * 0.25f; qv.w = A3 * 0.25f;
      float4 kv; kv.x = B0; kv.y = B1; kv.z = B2; kv.w = B3;
      *(float4*)(qb + off) = qv;
      *(float4*)(kb + off) = kv;
    } else {
      float4 bgv = *(const float4*)(bg + c0);
      float4 vv; vv.x = A0; vv.y = A1; vv.z = A2; vv.w = A3;
      float4 gv; gv.x = sigm(B0 + bgv.x); gv.y = sigm(B1 + bgv.y);
      gv.z = sigm(B2 + bgv.z); gv.w = sigm(B3 + bgv.w);
      *(float4*)(vb + off) = vv;
      *(float4*)(gb + off) = gv;
    }
  } else {
    __shared__ float wp[CPP * HH];
    __shared__ float gp[CPP];
    __shared__ float bp[CPP];
    if (tid < CPP * HH) wp[tid] = W_pair[tid];
    if (tid < CPP) { gp[tid] = gamma_p[tid]; bp[tid] = beta_p[tid]; }
    __syncthreads();

    const int i  = (b - 256) * 4 + (tid >> 7);   // token 0..2047
    const int w  = i >> 5;
    const int qq = i & 31;
    const int k  = tid & 127;
    const int j  = w * NQW + k - PADW;

    float bh[HH];
    if (j >= 0 && j < NTOK) {
      const float* p = pair + ((size_t)i * NTOK + j) * CPP;
      float x[CPP];
#pragma unroll
      for (int u = 0; u < CPP; u += 4) {
        float4 v = *(const float4*)(p + u);
        x[u] = v.x; x[u + 1] = v.y; x[u + 2] = v.z; x[u + 3] = v.w;
      }
      float s = 0.f;
#pragma unroll
      for (int c = 0; c < CPP; ++c) s += x[c];
      float mu = s * (1.0f / CPP);
      float vv = 0.f;
#pragma unroll
      for (int c = 0; c < CPP; ++c) { float d = x[c] - mu; vv = fmaf(d, d, vv); }
      float rs = rsqrtf(vv * (1.0f / CPP) + 1e-5f);
#pragma unroll
      for (int h = 0; h < HH; ++h) bh[h] = 0.f;
#pragma unroll
      for (int c = 0; c < CPP; ++c) {
        float y = (x[c] - mu) * rs * gp[c] + bp[c];
#pragma unroll
        for (int h = 0; h < HH; ++h) bh[h] = fmaf(y, wp[c * HH + h], bh[h]);
      }
    } else {
#pragma unroll
      for (int h = 0; h < HH; ++h) bh[h] = -10000.0f;
    }
#pragma unroll
    for (int h = 0; h < HH; ++h)
      bias[((size_t)((w * HH + h) * NQW + qq)) * NKW + k] = bh[h];
  }
}

// ---------------------------------------------------------------------------
// K2: attention per (window, head). 512 blocks x 256 threads.
// thread = (qg 0..15, t 0..15): owns q-rows {2qg,2qg+1}, k-cols {t+16*i}.
// probabilities stay in registers; PV is outer-product + 16-lane shfl reduce.
// ---------------------------------------------------------------------------
__global__ __launch_bounds__(256) void attn_kernel(
    const float* __restrict__ qb, const float* __restrict__ kb,
    const float* __restrict__ vb, const float* __restrict__ bias,
    float* __restrict__ ob)
{
  __shared__ float qs[NQW][20];
  __shared__ float ks[NKW][20];
  __shared__ float vs[NKW][20];
  __shared__ float bs[NQW][132];
  const int w   = blockIdx.x >> 3;
  const int h   = blockIdx.x & 7;
  const int tid = threadIdx.x;

  if (tid < 128) {
    int qr = tid >> 2, c4 = (tid & 3) * 4;
    float4 v = *(const float4*)(qb + (size_t)(w * NQW + qr) * CC + h * DHH + c4);
    *(float4*)(&qs[qr][c4]) = v;
  }
#pragma unroll
  for (int it = 0; it < 2; ++it) {
    int idx = tid + it * 256;          // 0..511
    int kr = idx >> 2, c4 = (idx & 3) * 4;
    int j = w * NQW + kr - PADW;
    float4 kv = make_float4(0.f, 0.f, 0.f, 0.f);
    float4 vv = make_float4(0.f, 0.f, 0.f, 0.f);
    if (j >= 0 && j < NTOK) {
      kv = *(const float4*)(kb + (size_t)j * CC + h * DHH + c4);
      vv = *(const float4*)(vb + (size_t)j * CC + h * DHH + c4);
    }
    *(float4*)(&ks[kr][c4]) = kv;
    *(float4*)(&vs[kr][c4]) = vv;
  }
  const float* bt = bias + (size_t)(w * HH + h) * NQW * NKW;
#pragma unroll
  for (int it = 0; it < 4; ++it) {
    int idx = tid + it * 256;          // 0..1023 float4 units
    int qr = idx >> 5, k4 = (idx & 31) * 4;
    float4 bv = *(const float4*)(bt + qr * NKW + k4);
    *(float4*)(&bs[qr][k4]) = bv;
  }
  __syncthreads();

  const int qg = tid >> 4;   // 0..15
  const int t  = tid & 15;   // 0..15
  const int r0 = qg * 2, r1 = r0 + 1;

  float4 qa0 = *(float4*)(&qs[r0][0]);
  float4 qa1 = *(float4*)(&qs[r0][4]);
  float4 qa2 = *(float4*)(&qs[r0][8]);
  float4 qa3 = *(float4*)(&qs[r0][12]);
  float4 qb0 = *(float4*)(&qs[r1][0]);
  float4 qb1 = *(float4*)(&qs[r1][4]);
  float4 qb2 = *(float4*)(&qs[r1][8]);
  float4 qb3 = *(float4*)(&qs[r1][12]);

  float l0[8], l1[8];
#pragma unroll
  for (int i = 0; i < 8; ++i) {
    int k = t + 16 * i;
    const float* kr = &ks[k][0];
    float4 k0 = *(const float4*)(kr);
    float4 k1 = *(const float4*)(kr + 4);
    float4 k2 = *(const float4*)(kr + 8);
    float4 k3 = *(const float4*)(kr + 12);
    float da = 0.f, db = 0.f;
    da = fmaf(qa0.x, k0.x, da); da = fmaf(qa0.y, k0.y, da);
    da = fmaf(qa0.z, k0.z, da); da = fmaf(qa0.w, k0.w, da);
    da = fmaf(qa1.x, k1.x, da); da = fmaf(qa1.y, k1.y, da);
    da = fmaf(qa1.z, k1.z, da); da = fmaf(qa1.w, k1.w, da);
    da = fmaf(qa2.x, k2.x, da); da = fmaf(qa2.y, k2.y, da);
    da = fmaf(qa2.z, k2.z, da); da = fmaf(qa2.w, k2.w, da);
    da = fmaf(qa3.x, k3.x, da); da = fmaf(qa3.y, k3.y, da);
    da = fmaf(qa3.z, k3.z, da); da = fmaf(qa3.w, k3.w, da);
    db = fmaf(qb0.x, k0.x, db); db = fmaf(qb0.y, k0.y, db);
    db = fmaf(qb0.z, k0.z, db); db = fmaf(qb0.w, k0.w, db);
    db = fmaf(qb1.x, k1.x, db); db = fmaf(qb1.y, k1.y, db);
    db = fmaf(qb1.z, k1.z, db); db = fmaf(qb1.w, k1.w, db);
    db = fmaf(qb2.x, k2.x, db); db = fmaf(qb2.y, k2.y, db);
    db = fmaf(qb2.z, k2.z, db); db = fmaf(qb2.w, k2.w, db);
    db = fmaf(qb3.x, k3.x, db); db = fmaf(qb3.y, k3.y, db);
    db = fmaf(qb3.z, k3.z, db); db = fmaf(qb3.w, k3.w, db);
    l0[i] = da + bs[r0][k];
    l1[i] = db + bs[r1][k];
  }

  float m0 = l0[0], m1 = l1[0];
#pragma unroll
  for (int i = 1; i < 8; ++i) { m0 = fmaxf(m0, l0[i]); m1 = fmaxf(m1, l1[i]); }
#pragma unroll
  for (int m = 1; m < 16; m <<= 1) {
    m0 = fmaxf(m0, __shfl_xor(m0, m));
    m1 = fmaxf(m1, __shfl_xor(m1, m));
  }
  float s0 = 0.f, s1 = 0.f;
  float p0[8], p1[8];
#pragma unroll
  for (int i = 0; i < 8; ++i) {
    p0[i] = expf(l0[i] - m0); s0 += p0[i];
    p1[i] = expf(l1[i] - m1); s1 += p1[i];
  }
#pragma unroll
  for (int m = 1; m < 16; m <<= 1) {
    s0 += __shfl_xor(s0, m);
    s1 += __shfl_xor(s1, m);
  }
  float inv0 = 1.0f / s0, inv1 = 1.0f / s1;
#pragma unroll
  for (int i = 0; i < 8; ++i) { p0[i] *= inv0; p1[i] *= inv1; }

  float o0[16], o1[16];
#pragma unroll
  for (int d = 0; d < 16; ++d) { o0[d] = 0.f; o1[d] = 0.f; }
#pragma unroll
  for (int i = 0; i < 8; ++i) {
    int k = t + 16 * i;
    const float* vr = &vs[k][0];
    float4 v0 = *(const float4*)(vr);
    float4 v1 = *(const float4*)(vr + 4);
    float4 v2 = *(const float4*)(vr + 8);
    float4 v3 = *(const float4*)(vr + 12);
    float pa = p0[i], pb = p1[i];
    o0[0]  = fmaf(pa, v0.x, o0[0]);  o0[1]  = fmaf(pa, v0.y, o0[1]);
    o0[2]  = fmaf(pa, v0.z, o0[2]);  o0[3]  = fmaf(pa, v0.w, o0[3]);
    o0[4]  = fmaf(pa, v1.x, o0[4]);  o0[5]  = fmaf(pa, v1.y, o0[5]);
    o0[6]  = fmaf(pa, v1.z, o0[6]);  o0[7]  = fmaf(pa, v1.w, o0[7]);
    o0[8]  = fmaf(pa, v2.x, o0[8]);  o0[9]  = fmaf(pa, v2.y, o0[9]);
    o0[10] = fmaf(pa, v2.z, o0[10]); o0[11] = fmaf(pa, v2.w, o0[11]);
    o0[12] = fmaf(pa, v3.x, o0[12]); o0[13] = fmaf(pa, v3.y, o0[13]);
    o0[14] = fmaf(pa, v3.z, o0[14]); o0[15] = fmaf(pa, v3.w, o0[15]);
    o1[0]  = fmaf(pb, v0.x, o1[0]);  o1[1]  = fmaf(pb, v0.y, o1[1]);
    o1[2]  = fmaf(pb, v0.z, o1[2]);  o1[3]  = fmaf(pb, v0.w, o1[3]);
    o1[4]  = fmaf(pb, v1.x, o1[4]);  o1[5]  = fmaf(pb, v1.y, o1[5]);
    o1[6]  = fmaf(pb, v1.z, o1[6]);  o1[7]  = fmaf(pb, v1.w, o1[7]);
    o1[8]  = fmaf(pb, v2.x, o1[8]);  o1[9]  = fmaf(pb, v2.y, o1[9]);
    o1[10] = fmaf(pb, v2.z, o1[10]); o1[11] = fmaf(pb, v2.w, o1[11]);
    o1[12] = fmaf(pb, v3.x, o1[12]); o1[13] = fmaf(pb, v3.y, o1[13]);
    o1[14] = fmaf(pb, v3.z, o1[14]); o1[15] = fmaf(pb, v3.w, o1[15]);
  }
#pragma unroll
  for (int d = 0; d < 16; ++d) {
#pragma unroll
    for (int m = 1; m < 16; m <<= 1) {
      o0[d] += __shfl_xor(o0[d], m);
      o1[d] += __shfl_xor(o1[d], m);
    }
  }
  float w0 = 0.f, w1 = 0.f;
#pragma unroll
  for (int d = 0; d < 16; ++d) {
    w0 = (t == d) ? o0[d] : w0;
    w1 = (t == d) ? o1[d] : w1;
  }
  ob[(size_t)(w * NQW + r0) * CC + h * DHH + t] = w0;
  ob[(size_t)(w * NQW + r1) * CC + h * DHH + t] = w1;
}

// ---------------------------------------------------------------------------
// K3: u = (o*g)@Wo + bo ; out = sigmoid(u@W_out + b_out) * u
// 256 blocks x 256 threads: 8 rows x 32 lanes, 4 cols (float4) per thread.
// wave = 2 rows -> W addresses merge across half-waves.
// ---------------------------------------------------------------------------
__global__ __launch_bounds__(256) void out_kernel(
    const float* __restrict__ ob_, const float* __restrict__ gb_,
    const float* __restrict__ Wo, const float* __restrict__ bo,
    const float* __restrict__ W_out, const float* __restrict__ b_out,
    float* __restrict__ out)
{
  __shared__ float og[8][132];
  __shared__ float us[8][132];
  const int tid = threadIdx.x;
  const int g   = tid >> 5;       // 0..7
  const int t   = tid & 31;
  const int c0  = t * 4;
  const int row = blockIdx.x * 8 + g;

  float4 o4 = *(const float4*)(ob_ + (size_t)row * CC + c0);
  float4 g4 = *(const float4*)(gb_ + (size_t)row * CC + c0);
  og[g][c0]     = o4.x * g4.x;
  og[g][c0 + 1] = o4.y * g4.y;
  og[g][c0 + 2] = o4.z * g4.z;
  og[g][c0 + 3] = o4.w * g4.w;
  __syncthreads();

  float u0 = 0.f, u1 = 0.f, u2 = 0.f, u3 = 0.f;
#pragma unroll 4
  for (int c = 0; c < CC; ++c) {
    float xv = og[g][c];
    float4 w = *(const float4*)(Wo + c * CC + c0);
    u0 = fmaf(xv, w.x, u0); u1 = fmaf(xv, w.y, u1);
    u2 = fmaf(xv, w.z, u2); u3 = fmaf(xv, w.w, u3);
  }
  float4 bov = *(const float4*)(bo + c0);
  u0 += bov.x; u1 += bov.y; u2 += bov.z; u3 += bov.w;
  us[g][c0]     = u0; us[g][c0 + 1] = u1;
  us[g][c0 + 2] = u2; us[g][c0 + 3] = u3;
  __syncthreads();

  float a0 = 0.f, a1 = 0.f, a2 = 0.f, a3 = 0.f;
#pragma unroll 4
  for (int c = 0; c < CC; ++c) {
    float xv = us[g][c];
    float4 w = *(const float4*)(W_out + c * CC + c0);
    a0 = fmaf(xv, w.x, a0); a1 = fmaf(xv, w.y, a1);
    a2 = fmaf(xv, w.z, a2); a3 = fmaf(xv, w.w, a3);
  }
  float4 bo2 = *(const float4*)(b_out + c0);
  float4 res;
  res.x = sigm(a0 + bo2.x) * u0;
  res.y = sigm(a1 + bo2.y) * u1;
  res.z = sigm(a2 + bo2.z) * u2;
  res.w = sigm(a3 + bo2.w) * u3;
  *(float4*)(out + (size_t)row * CC + c0) = res;
}

// ---------------------------------------------------------------------------
extern "C" void kernel_launch(void* const* d_in, const int* in_sizes, int n_in,
                              void* d_out, int out_size, void* d_ws, size_t ws_size,
                              hipStream_t stream) {
  (void)in_sizes; (void)n_in; (void)out_size; (void)ws_size;
  const float* x1      = (const float*)d_in[0];
  const float* x2      = (const float*)d_in[1];
  const float* pair    = (const float*)d_in[2];
  const float* gamma_s = (const float*)d_in[3];
  const float* Wg_ada  = (const float*)d_in[4];
  const float* bg_ada  = (const float*)d_in[5];
  const float* W_skip  = (const float*)d_in[6];
  const float* gamma_p = (const float*)d_in[7];
  const float* beta_p  = (const float*)d_in[8];
  const float* W_pair  = (const float*)d_in[9];
  const float* Wq      = (const float*)d_in[10];
  const float* Wk      = (const float*)d_in[11];
  const float* Wv      = (const float*)d_in[12];
  const float* Wg      = (const float*)d_in[13];
  const float* bg      = (const float*)d_in[14];
  const float* Wo      = (const float*)d_in[15];
  const float* bo      = (const float*)d_in[16];
  const float* W_out   = (const float*)d_in[17];
  const float* b_out   = (const float*)d_in[18];

  float* ws   = (float*)d_ws;
  const size_t NC = (size_t)NTOK * CC;   // 262144
  float* qb   = ws;
  float* kb   = ws + NC;
  float* vb   = ws + 2 * NC;
  float* gb   = ws + 3 * NC;
  float* obuf = ws + 4 * NC;
  float* bias = ws + 5 * NC;             // 64*8*32*128 = 2097152 floats

  fused1_kernel<<<768, 512, 0, stream>>>(x1, x2, gamma_s, Wg_ada, bg_ada,
                                         W_skip, Wq, Wk, Wv, Wg, bg,
                                         pair, gamma_p, beta_p, W_pair,
                                         qb, kb, vb, gb, bias);
  attn_kernel<<<NBW * HH, 256, 0, stream>>>(qb, kb, vb, bias, obuf);
  out_kernel<<<NTOK / 8, 256, 0, stream>>>(obuf, gb, Wo, bo, W_out, b_out,
                                           (float*)d_out);
}

// Round 4
// 50.283 us; speedup vs baseline: 1.8149x; 1.3934x over previous
//
#include <hip/hip_runtime.h>
#include <math.h>

#define NTOK 2048
#define CC   128
#define CPP  16
#define HH   8
#define DHH  16
#define NQW  32
#define NKW  128
#define PADW 48
#define NBW  64

__device__ __forceinline__ float sigm(float x) { return 1.0f / (1.0f + expf(-x)); }

// ---------------------------------------------------------------------------
// K1: blocks [0,512): stage-1 (adaLN) for 4 rows each -> writes aT (transposed)
//     blocks [512,1536): bias role, 2 tokens per block.
// 256 threads.
// stage-1: wave w owns row w for LN (lane-unique float2, 64-lane shfl reduce),
//   sln stored transposed in LDS At[128][6] (b64-aligned pad), aln kept in LDS.
//   GEMM: thread (rg=tid>>7, cg=tid&127): 2 rows x 1 col x 2 mats.
//   A: b64 all-lanes-same-addr broadcast (free); W: lane-unique dword (256B/wave).
// ---------------------------------------------------------------------------
__global__ __launch_bounds__(256) void k1_stage1_bias(
    const float* __restrict__ x1, const float* __restrict__ x2,
    const float* __restrict__ gamma_s,
    const float* __restrict__ Wg_ada, const float* __restrict__ bg_ada,
    const float* __restrict__ W_skip,
    const float* __restrict__ pair,
    const float* __restrict__ gamma_p, const float* __restrict__ beta_p,
    const float* __restrict__ W_pair,
    float* __restrict__ aT,          // [128][2048] transposed adaLN output
    float* __restrict__ bias)
{
  const int b   = blockIdx.x;
  const int tid = threadIdx.x;

  if (b < 512) {
    __shared__ float At[CC][6];        // sln transposed, pad 6 for b64 align
    __shared__ float aln_lds[4][132];
    const int r0 = b * 4;
    const int w  = tid >> 6;           // wave = row 0..3
    const int l  = tid & 63;
    const int c0 = l * 2;
    const int row = r0 + w;

    float2 v1 = *(const float2*)(x1 + (size_t)row * CC + c0);
    float2 v2 = *(const float2*)(x2 + (size_t)row * CC + c0);
    float s1 = v1.x + v1.y, p1 = v1.x * v1.x + v1.y * v1.y;
    float s2 = v2.x + v2.y, p2 = v2.x * v2.x + v2.y * v2.y;
#pragma unroll
    for (int m = 1; m < 64; m <<= 1) {
      s1 += __shfl_xor(s1, m); p1 += __shfl_xor(p1, m);
      s2 += __shfl_xor(s2, m); p2 += __shfl_xor(p2, m);
    }
    const float rc = 1.0f / 128.0f;
    float mu1 = s1 * rc, mu2 = s2 * rc;
    float rs1 = rsqrtf(p1 * rc - mu1 * mu1 + 1e-5f);
    float rs2 = rsqrtf(p2 * rc - mu2 * mu2 + 1e-5f);
    float2 gs = *(const float2*)(gamma_s + c0);
    At[c0][w]     = (v2.x - mu2) * rs2 * gs.x;
    At[c0 + 1][w] = (v2.y - mu2) * rs2 * gs.y;
    aln_lds[w][c0]     = (v1.x - mu1) * rs1;
    aln_lds[w][c0 + 1] = (v1.y - mu1) * rs1;
    __syncthreads();

    const int rg = tid >> 7;           // 0..1 (row pair)
    const int cg = tid & 127;          // col
    float g0 = 0.f, g1 = 0.f, sk0 = 0.f, sk1 = 0.f;
#pragma unroll 8
    for (int k = 0; k < CC; ++k) {
      float2 a2 = *(const float2*)(&At[k][rg * 2]);   // broadcast b64
      float wg  = Wg_ada[k * CC + cg];                 // lane-unique dword
      float wsk = W_skip[k * CC + cg];
      g0  = fmaf(a2.x, wg,  g0);  g1  = fmaf(a2.y, wg,  g1);
      sk0 = fmaf(a2.x, wsk, sk0); sk1 = fmaf(a2.y, wsk, sk1);
    }
    float bga = bg_ada[cg];
    float o0 = sigm(g0 + bga) * aln_lds[rg * 2][cg]     + sk0;
    float o1 = sigm(g1 + bga) * aln_lds[rg * 2 + 1][cg] + sk1;
    float2 o2; o2.x = o0; o2.y = o1;
    *(float2*)(aT + (size_t)cg * NTOK + r0 + rg * 2) = o2;
  } else {
    __shared__ float wp[CPP * HH];
    __shared__ float gp[CPP];
    __shared__ float bp[CPP];
    if (tid < CPP * HH) wp[tid] = W_pair[tid];
    if (tid < CPP) { gp[tid] = gamma_p[tid]; bp[tid] = beta_p[tid]; }
    __syncthreads();

    const int i  = (b - 512) * 2 + (tid >> 7);   // token 0..2047
    const int w  = i >> 5;
    const int qq = i & 31;
    const int k  = tid & 127;
    const int j  = w * NQW + k - PADW;

    float bh[HH];
    if (j >= 0 && j < NTOK) {
      const float* p = pair + ((size_t)i * NTOK + j) * CPP;
      float x[CPP];
#pragma unroll
      for (int u = 0; u < CPP; u += 4) {
        float4 v = *(const float4*)(p + u);
        x[u] = v.x; x[u + 1] = v.y; x[u + 2] = v.z; x[u + 3] = v.w;
      }
      float s = 0.f;
#pragma unroll
      for (int c = 0; c < CPP; ++c) s += x[c];
      float mu = s * (1.0f / CPP);
      float vv = 0.f;
#pragma unroll
      for (int c = 0; c < CPP; ++c) { float d = x[c] - mu; vv = fmaf(d, d, vv); }
      float rs = rsqrtf(vv * (1.0f / CPP) + 1e-5f);
#pragma unroll
      for (int h = 0; h < HH; ++h) bh[h] = 0.f;
#pragma unroll
      for (int c = 0; c < CPP; ++c) {
        float y = (x[c] - mu) * rs * gp[c] + bp[c];
#pragma unroll
        for (int h = 0; h < HH; ++h) bh[h] = fmaf(y, wp[c * HH + h], bh[h]);
      }
    } else {
#pragma unroll
      for (int h = 0; h < HH; ++h) bh[h] = -10000.0f;
    }
#pragma unroll
    for (int h = 0; h < HH; ++h)
      bias[((size_t)((w * HH + h) * NQW + qq)) * NKW + k] = bh[h];
  }
}

// ---------------------------------------------------------------------------
// K2: projections q,k,v,g from aT. 512 blocks x 256 threads, 4 rows/block.
// thread (m=tid>>6 selects matrix, cg=tid&63 -> 2 cols). A-operand arrives via
// wave-uniform loads of aT (compiler -> s_load -> SGPR broadcast, free pipe);
// W is lane-unique float2 (512B/wave, zero dup). acc = 4 rows x 2 cols.
// ---------------------------------------------------------------------------
__global__ __launch_bounds__(256) void k2_proj(
    const float* __restrict__ aT,
    const float* __restrict__ Wq, const float* __restrict__ Wk,
    const float* __restrict__ Wv, const float* __restrict__ Wg,
    const float* __restrict__ bg,
    float* __restrict__ qb, float* __restrict__ kb,
    float* __restrict__ vb, float* __restrict__ gb)
{
  const int r0  = blockIdx.x * 4;
  const int tid = threadIdx.x;
  const int m   = tid >> 6;          // 0..3: Wq,Wk,Wv,Wg (wave-uniform)
  const int cg  = tid & 63;
  const int c0  = cg * 2;

  const float* Wm = (m == 0) ? Wq : (m == 1) ? Wk : (m == 2) ? Wv : Wg;

  float a00 = 0.f, a01 = 0.f, a10 = 0.f, a11 = 0.f;
  float a20 = 0.f, a21 = 0.f, a30 = 0.f, a31 = 0.f;
#pragma unroll 8
  for (int k = 0; k < CC; ++k) {
    float4 av = *(const float4*)(aT + (size_t)k * NTOK + r0);  // uniform -> s_load
    float2 wv = *(const float2*)(Wm + k * CC + c0);
    a00 = fmaf(av.x, wv.x, a00); a01 = fmaf(av.x, wv.y, a01);
    a10 = fmaf(av.y, wv.x, a10); a11 = fmaf(av.y, wv.y, a11);
    a20 = fmaf(av.z, wv.x, a20); a21 = fmaf(av.z, wv.y, a21);
    a30 = fmaf(av.w, wv.x, a30); a31 = fmaf(av.w, wv.y, a31);
  }

  if (m == 0) {
    float2 r;
    r.x = a00 * 0.25f; r.y = a01 * 0.25f; *(float2*)(qb + (size_t)(r0 + 0) * CC + c0) = r;
    r.x = a10 * 0.25f; r.y = a11 * 0.25f; *(float2*)(qb + (size_t)(r0 + 1) * CC + c0) = r;
    r.x = a20 * 0.25f; r.y = a21 * 0.25f; *(float2*)(qb + (size_t)(r0 + 2) * CC + c0) = r;
    r.x = a30 * 0.25f; r.y = a31 * 0.25f; *(float2*)(qb + (size_t)(r0 + 3) * CC + c0) = r;
  } else if (m == 1) {
    float2 r;
    r.x = a00; r.y = a01; *(float2*)(kb + (size_t)(r0 + 0) * CC + c0) = r;
    r.x = a10; r.y = a11; *(float2*)(kb + (size_t)(r0 + 1) * CC + c0) = r;
    r.x = a20; r.y = a21; *(float2*)(kb + (size_t)(r0 + 2) * CC + c0) = r;
    r.x = a30; r.y = a31; *(float2*)(kb + (size_t)(r0 + 3) * CC + c0) = r;
  } else if (m == 2) {
    float2 r;
    r.x = a00; r.y = a01; *(float2*)(vb + (size_t)(r0 + 0) * CC + c0) = r;
    r.x = a10; r.y = a11; *(float2*)(vb + (size_t)(r0 + 1) * CC + c0) = r;
    r.x = a20; r.y = a21; *(float2*)(vb + (size_t)(r0 + 2) * CC + c0) = r;
    r.x = a30; r.y = a31; *(float2*)(vb + (size_t)(r0 + 3) * CC + c0) = r;
  } else {
    float2 bgv = *(const float2*)(bg + c0);
    float2 r;
    r.x = sigm(a00 + bgv.x); r.y = sigm(a01 + bgv.y); *(float2*)(gb + (size_t)(r0 + 0) * CC + c0) = r;
    r.x = sigm(a10 + bgv.x); r.y = sigm(a11 + bgv.y); *(float2*)(gb + (size_t)(r0 + 1) * CC + c0) = r;
    r.x = sigm(a20 + bgv.x); r.y = sigm(a21 + bgv.y); *(float2*)(gb + (size_t)(r0 + 2) * CC + c0) = r;
    r.x = sigm(a30 + bgv.x); r.y = sigm(a31 + bgv.y); *(float2*)(gb + (size_t)(r0 + 3) * CC + c0) = r;
  }
}

// ---------------------------------------------------------------------------
// K3: attention per (window, head). 512 blocks x 256 threads. (unchanged)
// ---------------------------------------------------------------------------
__global__ __launch_bounds__(256) void attn_kernel(
    const float* __restrict__ qb, const float* __restrict__ kb,
    const float* __restrict__ vb, const float* __restrict__ bias,
    float* __restrict__ ob)
{
  __shared__ float qs[NQW][20];
  __shared__ float ks[NKW][20];
  __shared__ float vs[NKW][20];
  __shared__ float bs[NQW][132];
  const int w   = blockIdx.x >> 3;
  const int h   = blockIdx.x & 7;
  const int tid = threadIdx.x;

  if (tid < 128) {
    int qr = tid >> 2, c4 = (tid & 3) * 4;
    float4 v = *(const float4*)(qb + (size_t)(w * NQW + qr) * CC + h * DHH + c4);
    *(float4*)(&qs[qr][c4]) = v;
  }
#pragma unroll
  for (int it = 0; it < 2; ++it) {
    int idx = tid + it * 256;
    int kr = idx >> 2, c4 = (idx & 3) * 4;
    int j = w * NQW + kr - PADW;
    float4 kv = make_float4(0.f, 0.f, 0.f, 0.f);
    float4 vv = make_float4(0.f, 0.f, 0.f, 0.f);
    if (j >= 0 && j < NTOK) {
      kv = *(const float4*)(kb + (size_t)j * CC + h * DHH + c4);
      vv = *(const float4*)(vb + (size_t)j * CC + h * DHH + c4);
    }
    *(float4*)(&ks[kr][c4]) = kv;
    *(float4*)(&vs[kr][c4]) = vv;
  }
  const float* bt = bias + (size_t)(w * HH + h) * NQW * NKW;
#pragma unroll
  for (int it = 0; it < 4; ++it) {
    int idx = tid + it * 256;
    int qr = idx >> 5, k4 = (idx & 31) * 4;
    float4 bv = *(const float4*)(bt + qr * NKW + k4);
    *(float4*)(&bs[qr][k4]) = bv;
  }
  __syncthreads();

  const int qg = tid >> 4;
  const int t  = tid & 15;
  const int r0 = qg * 2, r1 = r0 + 1;

  float4 qa0 = *(float4*)(&qs[r0][0]);
  float4 qa1 = *(float4*)(&qs[r0][4]);
  float4 qa2 = *(float4*)(&qs[r0][8]);
  float4 qa3 = *(float4*)(&qs[r0][12]);
  float4 qb0 = *(float4*)(&qs[r1][0]);
  float4 qb1 = *(float4*)(&qs[r1][4]);
  float4 qb2 = *(float4*)(&qs[r1][8]);
  float4 qb3 = *(float4*)(&qs[r1][12]);

  float l0[8], l1[8];
#pragma unroll
  for (int i = 0; i < 8; ++i) {
    int k = t + 16 * i;
    const float* kr = &ks[k][0];
    float4 k0 = *(const float4*)(kr);
    float4 k1 = *(const float4*)(kr + 4);
    float4 k2 = *(const float4*)(kr + 8);
    float4 k3 = *(const float4*)(kr + 12);
    float da = 0.f, db = 0.f;
    da = fmaf(qa0.x, k0.x, da); da = fmaf(qa0.y, k0.y, da);
    da = fmaf(qa0.z, k0.z, da); da = fmaf(qa0.w, k0.w, da);
    da = fmaf(qa1.x, k1.x, da); da = fmaf(qa1.y, k1.y, da);
    da = fmaf(qa1.z, k1.z, da); da = fmaf(qa1.w, k1.w, da);
    da = fmaf(qa2.x, k2.x, da); da = fmaf(qa2.y, k2.y, da);
    da = fmaf(qa2.z, k2.z, da); da = fmaf(qa2.w, k2.w, da);
    da = fmaf(qa3.x, k3.x, da); da = fmaf(qa3.y, k3.y, da);
    da = fmaf(qa3.z, k3.z, da); da = fmaf(qa3.w, k3.w, da);
    db = fmaf(qb0.x, k0.x, db); db = fmaf(qb0.y, k0.y, db);
    db = fmaf(qb0.z, k0.z, db); db = fmaf(qb0.w, k0.w, db);
    db = fmaf(qb1.x, k1.x, db); db = fmaf(qb1.y, k1.y, db);
    db = fmaf(qb1.z, k1.z, db); db = fmaf(qb1.w, k1.w, db);
    db = fmaf(qb2.x, k2.x, db); db = fmaf(qb2.y, k2.y, db);
    db = fmaf(qb2.z, k2.z, db); db = fmaf(qb2.w, k2.w, db);
    db = fmaf(qb3.x, k3.x, db); db = fmaf(qb3.y, k3.y, db);
    db = fmaf(qb3.z, k3.z, db); db = fmaf(qb3.w, k3.w, db);
    l0[i] = da + bs[r0][k];
    l1[i] = db + bs[r1][k];
  }

  float m0 = l0[0], m1 = l1[0];
#pragma unroll
  for (int i = 1; i < 8; ++i) { m0 = fmaxf(m0, l0[i]); m1 = fmaxf(m1, l1[i]); }
#pragma unroll
  for (int m = 1; m < 16; m <<= 1) {
    m0 = fmaxf(m0, __shfl_xor(m0, m));
    m1 = fmaxf(m1, __shfl_xor(m1, m));
  }
  float s0 = 0.f, s1 = 0.f;
  float p0[8], p1[8];
#pragma unroll
  for (int i = 0; i < 8; ++i) {
    p0[i] = expf(l0[i] - m0); s0 += p0[i];
    p1[i] = expf(l1[i] - m1); s1 += p1[i];
  }
#pragma unroll
  for (int m = 1; m < 16; m <<= 1) {
    s0 += __shfl_xor(s0, m);
    s1 += __shfl_xor(s1, m);
  }
  float inv0 = 1.0f / s0, inv1 = 1.0f / s1;
#pragma unroll
  for (int i = 0; i < 8; ++i) { p0[i] *= inv0; p1[i] *= inv1; }

  float o0[16], o1[16];
#pragma unroll
  for (int d = 0; d < 16; ++d) { o0[d] = 0.f; o1[d] = 0.f; }
#pragma unroll
  for (int i = 0; i < 8; ++i) {
    int k = t + 16 * i;
    const float* vr = &vs[k][0];
    float4 v0 = *(const float4*)(vr);
    float4 v1 = *(const float4*)(vr + 4);
    float4 v2 = *(const float4*)(vr + 8);
    float4 v3 = *(const float4*)(vr + 12);
    float pa = p0[i], pb = p1[i];
    o0[0]  = fmaf(pa, v0.x, o0[0]);  o0[1]  = fmaf(pa, v0.y, o0[1]);
    o0[2]  = fmaf(pa, v0.z, o0[2]);  o0[3]  = fmaf(pa, v0.w, o0[3]);
    o0[4]  = fmaf(pa, v1.x, o0[4]);  o0[5]  = fmaf(pa, v1.y, o0[5]);
    o0[6]  = fmaf(pa, v1.z, o0[6]);  o0[7]  = fmaf(pa, v1.w, o0[7]);
    o0[8]  = fmaf(pa, v2.x, o0[8]);  o0[9]  = fmaf(pa, v2.y, o0[9]);
    o0[10] = fmaf(pa, v2.z, o0[10]); o0[11] = fmaf(pa, v2.w, o0[11]);
    o0[12] = fmaf(pa, v3.x, o0[12]); o0[13] = fmaf(pa, v3.y, o0[13]);
    o0[14] = fmaf(pa, v3.z, o0[14]); o0[15] = fmaf(pa, v3.w, o0[15]);
    o1[0]  = fmaf(pb, v0.x, o1[0]);  o1[1]  = fmaf(pb, v0.y, o1[1]);
    o1[2]  = fmaf(pb, v0.z, o1[2]);  o1[3]  = fmaf(pb, v0.w, o1[3]);
    o1[4]  = fmaf(pb, v1.x, o1[4]);  o1[5]  = fmaf(pb, v1.y, o1[5]);
    o1[6]  = fmaf(pb, v1.z, o1[6]);  o1[7]  = fmaf(pb, v1.w, o1[7]);
    o1[8]  = fmaf(pb, v2.x, o1[8]);  o1[9]  = fmaf(pb, v2.y, o1[9]);
    o1[10] = fmaf(pb, v2.z, o1[10]); o1[11] = fmaf(pb, v2.w, o1[11]);
    o1[12] = fmaf(pb, v3.x, o1[12]); o1[13] = fmaf(pb, v3.y, o1[13]);
    o1[14] = fmaf(pb, v3.z, o1[14]); o1[15] = fmaf(pb, v3.w, o1[15]);
  }
#pragma unroll
  for (int d = 0; d < 16; ++d) {
#pragma unroll
    for (int m = 1; m < 16; m <<= 1) {
      o0[d] += __shfl_xor(o0[d], m);
      o1[d] += __shfl_xor(o1[d], m);
    }
  }
  float w0 = 0.f, w1 = 0.f;
#pragma unroll
  for (int d = 0; d < 16; ++d) {
    w0 = (t == d) ? o0[d] : w0;
    w1 = (t == d) ? o1[d] : w1;
  }
  ob[(size_t)(w * NQW + r0) * CC + h * DHH + t] = w0;
  ob[(size_t)(w * NQW + r1) * CC + h * DHH + t] = w1;
}

// ---------------------------------------------------------------------------
// K4: u = (o*g)@Wo + bo ; out = sigmoid(u@W_out + b_out) * u
// 512 blocks x 256 threads, 4 rows/block. A transposed in LDS (b64 broadcast),
// W lane-unique dword. thread (rg=tid>>7, cg=tid&127): 2 rows x 1 col.
// ---------------------------------------------------------------------------
__global__ __launch_bounds__(256) void k4_out(
    const float* __restrict__ ob_, const float* __restrict__ gb_,
    const float* __restrict__ Wo, const float* __restrict__ bo,
    const float* __restrict__ W_out, const float* __restrict__ b_out,
    float* __restrict__ out)
{
  __shared__ float ogT[CC][6];
  __shared__ float usT[CC][6];
  const int r0  = blockIdx.x * 4;
  const int tid = threadIdx.x;
  const int w   = tid >> 6;          // wave = row 0..3
  const int l   = tid & 63;
  const int c0  = l * 2;

  float2 o2 = *(const float2*)(ob_ + (size_t)(r0 + w) * CC + c0);
  float2 g2 = *(const float2*)(gb_ + (size_t)(r0 + w) * CC + c0);
  ogT[c0][w]     = o2.x * g2.x;
  ogT[c0 + 1][w] = o2.y * g2.y;
  __syncthreads();

  const int rg = tid >> 7;           // 0..1
  const int cg = tid & 127;
  float u0 = 0.f, u1 = 0.f;
#pragma unroll 8
  for (int k = 0; k < CC; ++k) {
    float2 a2 = *(const float2*)(&ogT[k][rg * 2]);   // broadcast b64
    float wv  = Wo[k * CC + cg];                      // lane-unique dword
    u0 = fmaf(a2.x, wv, u0);
    u1 = fmaf(a2.y, wv, u1);
  }
  float bov = bo[cg];
  u0 += bov; u1 += bov;
  float2 uw; uw.x = u0; uw.y = u1;
  *(float2*)(&usT[cg][rg * 2]) = uw;
  __syncthreads();

  float a0 = 0.f, a1 = 0.f;
#pragma unroll 8
  for (int k = 0; k < CC; ++k) {
    float2 a2 = *(const float2*)(&usT[k][rg * 2]);
    float wv  = W_out[k * CC + cg];
    a0 = fmaf(a2.x, wv, a0);
    a1 = fmaf(a2.y, wv, a1);
  }
  float bo2 = b_out[cg];
  out[(size_t)(r0 + rg * 2)     * CC + cg] = sigm(a0 + bo2) * u0;
  out[(size_t)(r0 + rg * 2 + 1) * CC + cg] = sigm(a1 + bo2) * u1;
}

// ---------------------------------------------------------------------------
extern "C" void kernel_launch(void* const* d_in, const int* in_sizes, int n_in,
                              void* d_out, int out_size, void* d_ws, size_t ws_size,
                              hipStream_t stream) {
  (void)in_sizes; (void)n_in; (void)out_size; (void)ws_size;
  const float* x1      = (const float*)d_in[0];
  const float* x2      = (const float*)d_in[1];
  const float* pair    = (const float*)d_in[2];
  const float* gamma_s = (const float*)d_in[3];
  const float* Wg_ada  = (const float*)d_in[4];
  const float* bg_ada  = (const float*)d_in[5];
  const float* W_skip  = (const float*)d_in[6];
  const float* gamma_p = (const float*)d_in[7];
  const float* beta_p  = (const float*)d_in[8];
  const float* W_pair  = (const float*)d_in[9];
  const float* Wq      = (const float*)d_in[10];
  const float* Wk      = (const float*)d_in[11];
  const float* Wv      = (const float*)d_in[12];
  const float* Wg      = (const float*)d_in[13];
  const float* bg      = (const float*)d_in[14];
  const float* Wo      = (const float*)d_in[15];
  const float* bo      = (const float*)d_in[16];
  const float* W_out   = (const float*)d_in[17];
  const float* b_out   = (const float*)d_in[18];

  float* ws   = (float*)d_ws;
  const size_t NC = (size_t)NTOK * CC;   // 262144
  float* qb   = ws;
  float* kb   = ws + NC;
  float* vb   = ws + 2 * NC;
  float* gb   = ws + 3 * NC;
  float* obuf = ws + 4 * NC;
  float* aT   = ws + 5 * NC;
  float* bias = ws + 6 * NC;             // 64*8*32*128 = 2097152 floats

  k1_stage1_bias<<<1536, 256, 0, stream>>>(x1, x2, gamma_s, Wg_ada, bg_ada,
                                           W_skip, pair, gamma_p, beta_p,
                                           W_pair, aT, bias);
  k2_proj<<<512, 256, 0, stream>>>(aT, Wq, Wk, Wv, Wg, bg, qb, kb, vb, gb);
  attn_kernel<<<NBW * HH, 256, 0, stream>>>(qb, kb, vb, bias, obuf);
  k4_out<<<512, 256, 0, stream>>>(obuf, gb, Wo, bo, W_out, b_out,
                                  (float*)d_out);
}

// Round 5
// 45.069 us; speedup vs baseline: 2.0249x; 1.1157x over previous
//
#include <hip/hip_runtime.h>
#include <math.h>

#define NTOK 2048
#define CC   128
#define CPP  16
#define HH   8
#define DHH  16
#define NQW  32
#define NKW  128
#define PADW 48
#define NBW  64

__device__ __forceinline__ float sigm(float x) { return 1.0f / (1.0f + expf(-x)); }

// ---------------------------------------------------------------------------
// K1: blocks [0,256): LN + adaLN GEMM + all 4 projections for 8 rows, in-LDS.
//     blocks [256,1280): bias (2 tokens each).
// ---------------------------------------------------------------------------
__global__ __launch_bounds__(256) void k1_fused(
    const float* __restrict__ x1, const float* __restrict__ x2,
    const float* __restrict__ gamma_s,
    const float* __restrict__ Wg_ada, const float* __restrict__ bg_ada,
    const float* __restrict__ W_skip,
    const float* __restrict__ Wq, const float* __restrict__ Wk,
    const float* __restrict__ Wv, const float* __restrict__ Wg,
    const float* __restrict__ bg,
    const float* __restrict__ pair,
    const float* __restrict__ gamma_p, const float* __restrict__ beta_p,
    const float* __restrict__ W_pair,
    float* __restrict__ qb, float* __restrict__ kb,
    float* __restrict__ vb, float* __restrict__ gb,
    float* __restrict__ bias)
{
  const int b   = blockIdx.x;
  const int tid = threadIdx.x;

  if (b < 256) {
    __shared__ float sln[8][132];
    __shared__ float aln[8][132];
    __shared__ float as_[8][132];
    const int r0 = b * 8;

    // ---- LN of 8 rows: 32 lanes per row, float4 per lane ----
    {
      const int r = tid >> 5, t = tid & 31, c0 = t * 4;
      const int row = r0 + r;
      float4 v1 = *(const float4*)(x1 + (size_t)row * CC + c0);
      float4 v2 = *(const float4*)(x2 + (size_t)row * CC + c0);
      float s1 = v1.x + v1.y + v1.z + v1.w;
      float p1 = v1.x * v1.x + v1.y * v1.y + v1.z * v1.z + v1.w * v1.w;
      float s2 = v2.x + v2.y + v2.z + v2.w;
      float p2 = v2.x * v2.x + v2.y * v2.y + v2.z * v2.z + v2.w * v2.w;
#pragma unroll
      for (int m = 1; m < 32; m <<= 1) {
        s1 += __shfl_xor(s1, m); p1 += __shfl_xor(p1, m);
        s2 += __shfl_xor(s2, m); p2 += __shfl_xor(p2, m);
      }
      const float rc = 1.0f / 128.0f;
      float mu1 = s1 * rc, mu2 = s2 * rc;
      float rs1 = rsqrtf(p1 * rc - mu1 * mu1 + 1e-5f);
      float rs2 = rsqrtf(p2 * rc - mu2 * mu2 + 1e-5f);
      float4 gs = *(const float4*)(gamma_s + c0);
      float4 al, sl;
      al.x = (v1.x - mu1) * rs1; al.y = (v1.y - mu1) * rs1;
      al.z = (v1.z - mu1) * rs1; al.w = (v1.w - mu1) * rs1;
      sl.x = (v2.x - mu2) * rs2 * gs.x; sl.y = (v2.y - mu2) * rs2 * gs.y;
      sl.z = (v2.z - mu2) * rs2 * gs.z; sl.w = (v2.w - mu2) * rs2 * gs.w;
      *(float4*)(&aln[r][c0]) = al;
      *(float4*)(&sln[r][c0]) = sl;
    }
    __syncthreads();

    // ---- stage-1 adaLN GEMM: thread (rh=tid>>7, cg=tid&127) -> 4 rows x 1 col
    {
      const int rh = tid >> 7, cg = tid & 127;
      float g0 = 0.f, g1 = 0.f, g2 = 0.f, g3 = 0.f;
      float s0 = 0.f, s1 = 0.f, s2 = 0.f, s3 = 0.f;
#pragma unroll 4
      for (int k4 = 0; k4 < 32; ++k4) {
        float4 a0 = *(const float4*)(&sln[rh * 4 + 0][k4 * 4]);
        float4 a1 = *(const float4*)(&sln[rh * 4 + 1][k4 * 4]);
        float4 a2 = *(const float4*)(&sln[rh * 4 + 2][k4 * 4]);
        float4 a3 = *(const float4*)(&sln[rh * 4 + 3][k4 * 4]);
#define S1STEP(AX, J) { \
        float wg = Wg_ada[(k4 * 4 + J) * CC + cg]; \
        float wk = W_skip[(k4 * 4 + J) * CC + cg]; \
        g0 = fmaf(a0.AX, wg, g0); g1 = fmaf(a1.AX, wg, g1); \
        g2 = fmaf(a2.AX, wg, g2); g3 = fmaf(a3.AX, wg, g3); \
        s0 = fmaf(a0.AX, wk, s0); s1 = fmaf(a1.AX, wk, s1); \
        s2 = fmaf(a2.AX, wk, s2); s3 = fmaf(a3.AX, wk, s3); }
        S1STEP(x, 0) S1STEP(y, 1) S1STEP(z, 2) S1STEP(w, 3)
#undef S1STEP
      }
      float bga = bg_ada[cg];
      as_[rh * 4 + 0][cg] = sigm(g0 + bga) * aln[rh * 4 + 0][cg] + s0;
      as_[rh * 4 + 1][cg] = sigm(g1 + bga) * aln[rh * 4 + 1][cg] + s1;
      as_[rh * 4 + 2][cg] = sigm(g2 + bga) * aln[rh * 4 + 2][cg] + s2;
      as_[rh * 4 + 3][cg] = sigm(g3 + bga) * aln[rh * 4 + 3][cg] + s3;
    }
    __syncthreads();

    // ---- projections: wave m = matrix, lane -> 2 cols, 8 rows ----
    {
      const int m  = tid >> 6;
      const int l  = tid & 63;
      const int c0 = l * 2;
      const float* Wm = (m == 0) ? Wq : (m == 1) ? Wk : (m == 2) ? Wv : Wg;
      float2 c0_ = {0.f, 0.f}, c1_ = {0.f, 0.f}, c2_ = {0.f, 0.f}, c3_ = {0.f, 0.f};
      float2 c4_ = {0.f, 0.f}, c5_ = {0.f, 0.f}, c6_ = {0.f, 0.f}, c7_ = {0.f, 0.f};
#pragma unroll 2
      for (int k4 = 0; k4 < 32; ++k4) {
        float4 ra0 = *(const float4*)(&as_[0][k4 * 4]);
        float4 ra1 = *(const float4*)(&as_[1][k4 * 4]);
        float4 ra2 = *(const float4*)(&as_[2][k4 * 4]);
        float4 ra3 = *(const float4*)(&as_[3][k4 * 4]);
        float4 ra4 = *(const float4*)(&as_[4][k4 * 4]);
        float4 ra5 = *(const float4*)(&as_[5][k4 * 4]);
        float4 ra6 = *(const float4*)(&as_[6][k4 * 4]);
        float4 ra7 = *(const float4*)(&as_[7][k4 * 4]);
#define PJSTEP(AX, J) { \
        float2 wv = *(const float2*)(Wm + (k4 * 4 + J) * CC + c0); \
        c0_.x = fmaf(ra0.AX, wv.x, c0_.x); c0_.y = fmaf(ra0.AX, wv.y, c0_.y); \
        c1_.x = fmaf(ra1.AX, wv.x, c1_.x); c1_.y = fmaf(ra1.AX, wv.y, c1_.y); \
        c2_.x = fmaf(ra2.AX, wv.x, c2_.x); c2_.y = fmaf(ra2.AX, wv.y, c2_.y); \
        c3_.x = fmaf(ra3.AX, wv.x, c3_.x); c3_.y = fmaf(ra3.AX, wv.y, c3_.y); \
        c4_.x = fmaf(ra4.AX, wv.x, c4_.x); c4_.y = fmaf(ra4.AX, wv.y, c4_.y); \
        c5_.x = fmaf(ra5.AX, wv.x, c5_.x); c5_.y = fmaf(ra5.AX, wv.y, c5_.y); \
        c6_.x = fmaf(ra6.AX, wv.x, c6_.x); c6_.y = fmaf(ra6.AX, wv.y, c6_.y); \
        c7_.x = fmaf(ra7.AX, wv.x, c7_.x); c7_.y = fmaf(ra7.AX, wv.y, c7_.y); }
        PJSTEP(x, 0) PJSTEP(y, 1) PJSTEP(z, 2) PJSTEP(w, 3)
#undef PJSTEP
      }
      if (m == 0) {
#define QST(I, CI) { float2 r; r.x = CI.x * 0.25f; r.y = CI.y * 0.25f; \
        *(float2*)(qb + (size_t)(r0 + I) * CC + c0) = r; }
        QST(0, c0_) QST(1, c1_) QST(2, c2_) QST(3, c3_)
        QST(4, c4_) QST(5, c5_) QST(6, c6_) QST(7, c7_)
#undef QST
      } else if (m == 1) {
#define KST(I, CI) *(float2*)(kb + (size_t)(r0 + I) * CC + c0) = CI;
        KST(0, c0_) KST(1, c1_) KST(2, c2_) KST(3, c3_)
        KST(4, c4_) KST(5, c5_) KST(6, c6_) KST(7, c7_)
#undef KST
      } else if (m == 2) {
#define VST(I, CI) *(float2*)(vb + (size_t)(r0 + I) * CC + c0) = CI;
        VST(0, c0_) VST(1, c1_) VST(2, c2_) VST(3, c3_)
        VST(4, c4_) VST(5, c5_) VST(6, c6_) VST(7, c7_)
#undef VST
      } else {
        float2 bgv = *(const float2*)(bg + c0);
#define GST(I, CI) { float2 r; r.x = sigm(CI.x + bgv.x); r.y = sigm(CI.y + bgv.y); \
        *(float2*)(gb + (size_t)(r0 + I) * CC + c0) = r; }
        GST(0, c0_) GST(1, c1_) GST(2, c2_) GST(3, c3_)
        GST(4, c4_) GST(5, c5_) GST(6, c6_) GST(7, c7_)
#undef GST
      }
    }
  } else {
    __shared__ float wp[CPP * HH];
    __shared__ float gp[CPP];
    __shared__ float bp[CPP];
    if (tid < CPP * HH) wp[tid] = W_pair[tid];
    if (tid < CPP) { gp[tid] = gamma_p[tid]; bp[tid] = beta_p[tid]; }
    __syncthreads();

    const int i  = (b - 256) * 2 + (tid >> 7);   // token 0..2047
    const int w  = i >> 5;
    const int qq = i & 31;
    const int k  = tid & 127;
    const int j  = w * NQW + k - PADW;

    float bh[HH];
    if (j >= 0 && j < NTOK) {
      const float* p = pair + ((size_t)i * NTOK + j) * CPP;
      float x[CPP];
#pragma unroll
      for (int u = 0; u < CPP; u += 4) {
        float4 v = *(const float4*)(p + u);
        x[u] = v.x; x[u + 1] = v.y; x[u + 2] = v.z; x[u + 3] = v.w;
      }
      float s = 0.f;
#pragma unroll
      for (int c = 0; c < CPP; ++c) s += x[c];
      float mu = s * (1.0f / CPP);
      float vv = 0.f;
#pragma unroll
      for (int c = 0; c < CPP; ++c) { float d = x[c] - mu; vv = fmaf(d, d, vv); }
      float rs = rsqrtf(vv * (1.0f / CPP) + 1e-5f);
#pragma unroll
      for (int h = 0; h < HH; ++h) bh[h] = 0.f;
#pragma unroll
      for (int c = 0; c < CPP; ++c) {
        float y = (x[c] - mu) * rs * gp[c] + bp[c];
#pragma unroll
        for (int h = 0; h < HH; ++h) bh[h] = fmaf(y, wp[c * HH + h], bh[h]);
      }
    } else {
#pragma unroll
      for (int h = 0; h < HH; ++h) bh[h] = -10000.0f;
    }
#pragma unroll
    for (int h = 0; h < HH; ++h)
      bias[((size_t)((w * HH + h) * NQW + qq)) * NKW + k] = bh[h];
  }
}

// ---------------------------------------------------------------------------
// K2: attention, 1024 blocks x 256 threads: block = (window, head, q-half).
// 16 q-rows per block; thread = (qr=tid>>4, t=tid&15) -> 1 q-row, 8 k-cols.
// ---------------------------------------------------------------------------
__global__ __launch_bounds__(256) void attn_kernel(
    const float* __restrict__ qb, const float* __restrict__ kb,
    const float* __restrict__ vb, const float* __restrict__ bias,
    float* __restrict__ ob)
{
  __shared__ float qs[16][20];
  __shared__ float ks[NKW][20];
  __shared__ float vs[NKW][20];
  __shared__ float bs[16][132];
  const int u   = blockIdx.x;
  const int w   = u >> 4;
  const int h   = (u >> 1) & 7;
  const int qh  = u & 1;
  const int tid = threadIdx.x;

  if (tid < 64) {
    int qr = tid >> 2, c4 = (tid & 3) * 4;
    float4 v = *(const float4*)(qb + (size_t)(w * NQW + qh * 16 + qr) * CC + h * DHH + c4);
    *(float4*)(&qs[qr][c4]) = v;
  }
  {
    int kr = tid >> 1, c8 = (tid & 1) * 8;
    int j = w * NQW + kr - PADW;
    float4 k0 = make_float4(0.f, 0.f, 0.f, 0.f), k1 = k0, v0 = k0, v1 = k0;
    if (j >= 0 && j < NTOK) {
      const float* kp = kb + (size_t)j * CC + h * DHH + c8;
      const float* vp = vb + (size_t)j * CC + h * DHH + c8;
      k0 = *(const float4*)(kp);     k1 = *(const float4*)(kp + 4);
      v0 = *(const float4*)(vp);     v1 = *(const float4*)(vp + 4);
    }
    *(float4*)(&ks[kr][c8])     = k0;
    *(float4*)(&ks[kr][c8 + 4]) = k1;
    *(float4*)(&vs[kr][c8])     = v0;
    *(float4*)(&vs[kr][c8 + 4]) = v1;
  }
  {
    const float* bt = bias + (size_t)(w * HH + h) * NQW * NKW + (size_t)qh * 16 * NKW;
    int qr = tid >> 4, k8 = (tid & 15) * 8;
    float4 b0 = *(const float4*)(bt + qr * NKW + k8);
    float4 b1 = *(const float4*)(bt + qr * NKW + k8 + 4);
    *(float4*)(&bs[qr][k8])     = b0;
    *(float4*)(&bs[qr][k8 + 4]) = b1;
  }
  __syncthreads();

  const int qr = tid >> 4;   // 0..15
  const int t  = tid & 15;   // 0..15
  float4 q0 = *(float4*)(&qs[qr][0]);
  float4 q1 = *(float4*)(&qs[qr][4]);
  float4 q2 = *(float4*)(&qs[qr][8]);
  float4 q3 = *(float4*)(&qs[qr][12]);

  float l[8];
#pragma unroll
  for (int i = 0; i < 8; ++i) {
    int k = t + 16 * i;
    const float* kr_ = &ks[k][0];
    float4 k0 = *(const float4*)(kr_);
    float4 k1 = *(const float4*)(kr_ + 4);
    float4 k2 = *(const float4*)(kr_ + 8);
    float4 k3 = *(const float4*)(kr_ + 12);
    float d = 0.f;
    d = fmaf(q0.x, k0.x, d); d = fmaf(q0.y, k0.y, d);
    d = fmaf(q0.z, k0.z, d); d = fmaf(q0.w, k0.w, d);
    d = fmaf(q1.x, k1.x, d); d = fmaf(q1.y, k1.y, d);
    d = fmaf(q1.z, k1.z, d); d = fmaf(q1.w, k1.w, d);
    d = fmaf(q2.x, k2.x, d); d = fmaf(q2.y, k2.y, d);
    d = fmaf(q2.z, k2.z, d); d = fmaf(q2.w, k2.w, d);
    d = fmaf(q3.x, k3.x, d); d = fmaf(q3.y, k3.y, d);
    d = fmaf(q3.z, k3.z, d); d = fmaf(q3.w, k3.w, d);
    l[i] = d + bs[qr][k];
  }

  float m0 = l[0];
#pragma unroll
  for (int i = 1; i < 8; ++i) m0 = fmaxf(m0, l[i]);
  m0 = fmaxf(m0, __shfl_xor(m0, 1));
  m0 = fmaxf(m0, __shfl_xor(m0, 2));
  m0 = fmaxf(m0, __shfl_xor(m0, 4));
  m0 = fmaxf(m0, __shfl_xor(m0, 8));
  float s = 0.f;
  float p[8];
#pragma unroll
  for (int i = 0; i < 8; ++i) { p[i] = expf(l[i] - m0); s += p[i]; }
  s += __shfl_xor(s, 1);
  s += __shfl_xor(s, 2);
  s += __shfl_xor(s, 4);
  s += __shfl_xor(s, 8);
  float inv = 1.0f / s;
#pragma unroll
  for (int i = 0; i < 8; ++i) p[i] *= inv;

  float o[16];
#pragma unroll
  for (int d = 0; d < 16; ++d) o[d] = 0.f;
#pragma unroll
  for (int i = 0; i < 8; ++i) {
    int k = t + 16 * i;
    const float* vr = &vs[k][0];
    float4 v0 = *(const float4*)(vr);
    float4 v1 = *(const float4*)(vr + 4);
    float4 v2 = *(const float4*)(vr + 8);
    float4 v3 = *(const float4*)(vr + 12);
    float pa = p[i];
    o[0]  = fmaf(pa, v0.x, o[0]);  o[1]  = fmaf(pa, v0.y, o[1]);
    o[2]  = fmaf(pa, v0.z, o[2]);  o[3]  = fmaf(pa, v0.w, o[3]);
    o[4]  = fmaf(pa, v1.x, o[4]);  o[5]  = fmaf(pa, v1.y, o[5]);
    o[6]  = fmaf(pa, v1.z, o[6]);  o[7]  = fmaf(pa, v1.w, o[7]);
    o[8]  = fmaf(pa, v2.x, o[8]);  o[9]  = fmaf(pa, v2.y, o[9]);
    o[10] = fmaf(pa, v2.z, o[10]); o[11] = fmaf(pa, v2.w, o[11]);
    o[12] = fmaf(pa, v3.x, o[12]); o[13] = fmaf(pa, v3.y, o[13]);
    o[14] = fmaf(pa, v3.z, o[14]); o[15] = fmaf(pa, v3.w, o[15]);
  }
#pragma unroll
  for (int d = 0; d < 16; ++d) {
#pragma unroll
    for (int m = 1; m < 16; m <<= 1) o[d] += __shfl_xor(o[d], m);
  }
  float wsel = 0.f;
#pragma unroll
  for (int d = 0; d < 16; ++d) wsel = (t == d) ? o[d] : wsel;
  ob[(size_t)(w * NQW + qh * 16 + qr) * CC + h * DHH + t] = wsel;
}

// ---------------------------------------------------------------------------
// K3: u = (o*g)@Wo + bo ; out = sigmoid(u@W_out + b_out) * u
// 256 blocks x 256 threads, 8 rows/block, A via row-major LDS broadcast.
// ---------------------------------------------------------------------------
__global__ __launch_bounds__(256) void k3_out(
    const float* __restrict__ ob_, const float* __restrict__ gb_,
    const float* __restrict__ Wo, const float* __restrict__ bo,
    const float* __restrict__ W_out, const float* __restrict__ b_out,
    float* __restrict__ out)
{
  __shared__ float og[8][132];
  __shared__ float us[8][132];
  const int r0  = blockIdx.x * 8;
  const int tid = threadIdx.x;
  {
    const int r = tid >> 5, t = tid & 31, c0 = t * 4;
    float4 o4 = *(const float4*)(ob_ + (size_t)(r0 + r) * CC + c0);
    float4 g4 = *(const float4*)(gb_ + (size_t)(r0 + r) * CC + c0);
    float4 m4;
    m4.x = o4.x * g4.x; m4.y = o4.y * g4.y;
    m4.z = o4.z * g4.z; m4.w = o4.w * g4.w;
    *(float4*)(&og[r][c0]) = m4;
  }
  __syncthreads();

  const int rh = tid >> 7, cg = tid & 127;
  float u0 = 0.f, u1 = 0.f, u2 = 0.f, u3 = 0.f;
#pragma unroll 4
  for (int k4 = 0; k4 < 32; ++k4) {
    float4 a0 = *(const float4*)(&og[rh * 4 + 0][k4 * 4]);
    float4 a1 = *(const float4*)(&og[rh * 4 + 1][k4 * 4]);
    float4 a2 = *(const float4*)(&og[rh * 4 + 2][k4 * 4]);
    float4 a3 = *(const float4*)(&og[rh * 4 + 3][k4 * 4]);
#define O1STEP(AX, J) { \
    float wv = Wo[(k4 * 4 + J) * CC + cg]; \
    u0 = fmaf(a0.AX, wv, u0); u1 = fmaf(a1.AX, wv, u1); \
    u2 = fmaf(a2.AX, wv, u2); u3 = fmaf(a3.AX, wv, u3); }
    O1STEP(x, 0) O1STEP(y, 1) O1STEP(z, 2) O1STEP(w, 3)
#undef O1STEP
  }
  float bov = bo[cg];
  u0 += bov; u1 += bov; u2 += bov; u3 += bov;
  us[rh * 4 + 0][cg] = u0;
  us[rh * 4 + 1][cg] = u1;
  us[rh * 4 + 2][cg] = u2;
  us[rh * 4 + 3][cg] = u3;
  __syncthreads();

  float a0s = 0.f, a1s = 0.f, a2s = 0.f, a3s = 0.f;
#pragma unroll 4
  for (int k4 = 0; k4 < 32; ++k4) {
    float4 a0 = *(const float4*)(&us[rh * 4 + 0][k4 * 4]);
    float4 a1 = *(const float4*)(&us[rh * 4 + 1][k4 * 4]);
    float4 a2 = *(const float4*)(&us[rh * 4 + 2][k4 * 4]);
    float4 a3 = *(const float4*)(&us[rh * 4 + 3][k4 * 4]);
#define O2STEP(AX, J) { \
    float wv = W_out[(k4 * 4 + J) * CC + cg]; \
    a0s = fmaf(a0.AX, wv, a0s); a1s = fmaf(a1.AX, wv, a1s); \
    a2s = fmaf(a2.AX, wv, a2s); a3s = fmaf(a3.AX, wv, a3s); }
    O2STEP(x, 0) O2STEP(y, 1) O2STEP(z, 2) O2STEP(w, 3)
#undef O2STEP
  }
  float b2 = b_out[cg];
  out[(size_t)(r0 + rh * 4 + 0) * CC + cg] = sigm(a0s + b2) * u0;
  out[(size_t)(r0 + rh * 4 + 1) * CC + cg] = sigm(a1s + b2) * u1;
  out[(size_t)(r0 + rh * 4 + 2) * CC + cg] = sigm(a2s + b2) * u2;
  out[(size_t)(r0 + rh * 4 + 3) * CC + cg] = sigm(a3s + b2) * u3;
}

// ---------------------------------------------------------------------------
extern "C" void kernel_launch(void* const* d_in, const int* in_sizes, int n_in,
                              void* d_out, int out_size, void* d_ws, size_t ws_size,
                              hipStream_t stream) {
  (void)in_sizes; (void)n_in; (void)out_size; (void)ws_size;
  const float* x1      = (const float*)d_in[0];
  const float* x2      = (const float*)d_in[1];
  const float* pair    = (const float*)d_in[2];
  const float* gamma_s = (const float*)d_in[3];
  const float* Wg_ada  = (const float*)d_in[4];
  const float* bg_ada  = (const float*)d_in[5];
  const float* W_skip  = (const float*)d_in[6];
  const float* gamma_p = (const float*)d_in[7];
  const float* beta_p  = (const float*)d_in[8];
  const float* W_pair  = (const float*)d_in[9];
  const float* Wq      = (const float*)d_in[10];
  const float* Wk      = (const float*)d_in[11];
  const float* Wv      = (const float*)d_in[12];
  const float* Wg      = (const float*)d_in[13];
  const float* bg      = (const float*)d_in[14];
  const float* Wo      = (const float*)d_in[15];
  const float* bo      = (const float*)d_in[16];
  const float* W_out   = (const float*)d_in[17];
  const float* b_out   = (const float*)d_in[18];

  float* ws   = (float*)d_ws;
  const size_t NC = (size_t)NTOK * CC;   // 262144
  float* qb   = ws;
  float* kb   = ws + NC;
  float* vb   = ws + 2 * NC;
  float* gb   = ws + 3 * NC;
  float* obuf = ws + 4 * NC;
  float* bias = ws + 5 * NC;             // 64*8*32*128 = 2097152 floats

  k1_fused<<<1280, 256, 0, stream>>>(x1, x2, gamma_s, Wg_ada, bg_ada, W_skip,
                                     Wq, Wk, Wv, Wg, bg,
                                     pair, gamma_p, beta_p, W_pair,
                                     qb, kb, vb, gb, bias);
  attn_kernel<<<1024, 256, 0, stream>>>(qb, kb, vb, bias, obuf);
  k3_out<<<256, 256, 0, stream>>>(obuf, gb, Wo, bo, W_out, b_out,
                                  (float*)d_out);
}